// Round 6
// baseline (524.256 us; speedup 1.0000x reference)
//
#include <hip/hip_runtime.h>
#include <hip/hip_bf16.h>

typedef __hip_bfloat16 bf16;

typedef __bf16 bfrag8 __attribute__((ext_vector_type(8)));
typedef __bf16 bfrag4 __attribute__((ext_vector_type(4)));
typedef float  ffrag4 __attribute__((ext_vector_type(4)));
typedef float  ffrag16 __attribute__((ext_vector_type(16)));

// B=4, T=12, P=196, D=512, H=8, DH=64 ; M = B*T*P = 9408 = 73.5*128
#define EPS 1e-6f

__device__ __forceinline__ float gelu_exact(float v) {
  return 0.5f * v * (1.0f + erff(v * 0.7071067811865475f));
}

__device__ __forceinline__ void async16(const void* g, void* s) {
  __builtin_amdgcn_global_load_lds(
      (const __attribute__((address_space(1))) unsigned int*)g,
      (__attribute__((address_space(3))) unsigned int*)s, 16, 0, 0);
}

// pack two f32 -> one dword of 2 bf16 (lo = a, hi = b)
__device__ __forceinline__ int cvt_pk_bf16(float a, float b) {
  int r;
  asm("v_cvt_pk_bf16_f32 %0, %1, %2" : "=v"(r) : "v"(a), "v"(b));
  return r;
}
// vdst.hi32lanes <-> vsrc.lo32lanes
__device__ __forceinline__ void perm_swap(int& a, int& b) {
  asm volatile("v_permlane32_swap_b32 %0, %1" : "+v"(a), "+v"(b));
}

struct alignas(16) bf16x8 { bf16 v[8]; };
struct alignas(4)  bf16p2 { __bf16 v[2]; };

// ---------------- weight convert f32 -> bf16, packed region ----------------
// Wt is transposed [u][e][d] -> [e][u][d] so tc's B-rows are contiguous (K=6144)
__global__ __launch_bounds__(256) void conv_w_kernel(
    const float* __restrict__ Wq, const float* __restrict__ Wk,
    const float* __restrict__ Wv, const float* __restrict__ W1,
    const float* __restrict__ W2, const float* __restrict__ Wt,
    __bf16* __restrict__ dst)
{
  size_t e = ((size_t)blockIdx.x * 256 + threadIdx.x) * 8;
  const float* src; size_t off, dsto;
  if      (e <  262144) { src = Wq; off = e;           dsto = e; }
  else if (e <  524288) { src = Wk; off = e -  262144; dsto = e; }
  else if (e <  786432) { src = Wv; off = e -  524288; dsto = e; }
  else if (e < 1310720) { src = W1; off = e -  786432; dsto = e; }
  else if (e < 1835008) { src = W2; off = e - 1310720; dsto = e; }
  else if (e < 4980736) {
    src = Wt; off = e - 1835008;
    size_t u = off >> 18;            // / (512*512)
    size_t rem = off & 262143;
    size_t eo = rem >> 9, d = rem & 511;
    dsto = 1835008 + eo * 6144 + u * 512 + d;   // [e][u*512+d]
  }
  else return;
  float4 f0 = *(const float4*)(src + off);
  float4 f1 = *(const float4*)(src + off + 4);
  bfrag8 o;
  o[0] = (__bf16)f0.x; o[1] = (__bf16)f0.y; o[2] = (__bf16)f0.z; o[3] = (__bf16)f0.w;
  o[4] = (__bf16)f1.x; o[5] = (__bf16)f1.y; o[6] = (__bf16)f1.z; o[7] = (__bf16)f1.w;
  *(bfrag8*)(dst + dsto) = o;
}

__global__ __launch_bounds__(512) void sum_bt_kernel(
    const float* __restrict__ bt, float* __restrict__ sbt)
{
  int n = threadIdx.x;
  float s = 0.f;
#pragma unroll
  for (int u = 0; u < 12; ++u) s += bt[u * 512 + n];
  sbt[n] = s;
}

// ------------- LayerNorm f32 -> bf16, one 64-thread block per row of 512 ----
__global__ __launch_bounds__(64) void norm_f32_to_bf16_kernel(
    const float* __restrict__ in, __bf16* __restrict__ out,
    const float* __restrict__ alpha, const float* __restrict__ beta)
{
  size_t row = blockIdx.x;
  int l = threadIdx.x;
  const float* r = in + row * 512 + l * 8;
  float4 v0 = *(const float4*)(r);
  float4 v1 = *(const float4*)(r + 4);
  float f[8] = {v0.x, v0.y, v0.z, v0.w, v1.x, v1.y, v1.z, v1.w};
  float s = 0.f, ss = 0.f;
#pragma unroll
  for (int q = 0; q < 8; ++q) { s += f[q]; ss += f[q] * f[q]; }
#pragma unroll
  for (int off = 32; off; off >>= 1) { s += __shfl_xor(s, off); ss += __shfl_xor(ss, off); }
  float mu = s * (1.f / 512.f);
  float var = fmaxf((ss - 512.f * mu * mu) * (1.f / 511.f), 0.f);
  float inv = 1.f / (sqrtf(var) + EPS);
  const float* al = alpha + l * 8;
  const float* be = beta + l * 8;
  float4 a0 = *(const float4*)al, a1 = *(const float4*)(al + 4);
  float4 b0 = *(const float4*)be, b1 = *(const float4*)(be + 4);
  float aa[8] = {a0.x, a0.y, a0.z, a0.w, a1.x, a1.y, a1.z, a1.w};
  float bb[8] = {b0.x, b0.y, b0.z, b0.w, b1.x, b1.y, b1.z, b1.w};
  bfrag8 o;
#pragma unroll
  for (int q = 0; q < 8; ++q) o[q] = (__bf16)(aa[q] * (f[q] - mu) * inv + bb[q]);
  *(bfrag8*)(out + row * 512 + l * 8) = o;
}

// ------------- LayerNorm bf16 in-place + pos add; 4 rows per 256-thr block --
__global__ __launch_bounds__(256) void norm_av_kernel(
    bf16* __restrict__ av, const float* __restrict__ alpha,
    const float* __restrict__ beta, const float* __restrict__ pos)
{
  size_t row = (size_t)blockIdx.x * 4 + (threadIdx.x >> 6);  // [0, B*T*T*P)
  int l = threadIdx.x & 63;
  bf16* r = av + row * 512 + (size_t)l * 8;
  bf16x8 ib = *(const bf16x8*)r;
  float f[8];
#pragma unroll
  for (int q = 0; q < 8; ++q) f[q] = __bfloat162float(ib.v[q]);
  float s = 0.f, ss = 0.f;
#pragma unroll
  for (int q = 0; q < 8; ++q) { s += f[q]; ss += f[q] * f[q]; }
#pragma unroll
  for (int off = 32; off; off >>= 1) { s += __shfl_xor(s, off); ss += __shfl_xor(ss, off); }
  float mu = s * (1.f / 512.f);
  float var = fmaxf((ss - 512.f * mu * mu) * (1.f / 511.f), 0.f);
  float inv = 1.f / (sqrtf(var) + EPS);
  size_t prow = row % 28224;        // T*T*P  (pos broadcasts over batch)
  const float* pr = pos + prow * 512 + l * 8;
  float4 p0 = *(const float4*)pr, p1 = *(const float4*)(pr + 4);
  const float* al = alpha + l * 8;
  const float* be = beta + l * 8;
  float4 a0 = *(const float4*)al, a1 = *(const float4*)(al + 4);
  float4 b0 = *(const float4*)be, b1 = *(const float4*)(be + 4);
  float pa[8] = {p0.x, p0.y, p0.z, p0.w, p1.x, p1.y, p1.z, p1.w};
  float aa[8] = {a0.x, a0.y, a0.z, a0.w, a1.x, a1.y, a1.z, a1.w};
  float bb[8] = {b0.x, b0.y, b0.z, b0.w, b1.x, b1.y, b1.z, b1.w};
  bf16x8 ob;
#pragma unroll
  for (int q = 0; q < 8; ++q)
    ob.v[q] = __float2bfloat16(aa[q] * (f[q] - mu) * inv + bb[q] + pa[q]);
  *(bf16x8*)r = ob;
}

// ------------- MFMA NT GEMM, 128x128 tile, BK=32, 3-buffer pipeline ---------
// Depth-2 prefetch, ONE raw barrier per K-step, counted vmcnt(4) (never 0 in
// steady state). LDS slot swizzle on both sides. Chunked XCD swizzle.
// mode 0: fused QKV (N=1536), out bf16 +bias; mode 1: MLP1, out bf16 gelu;
// mode 2: MLP2, out f32 = res + gelu(acc+bias)
__global__ __launch_bounds__(256) void mfma_nt_kernel(
    const __bf16* __restrict__ A,
    const __bf16* __restrict__ Bq, const __bf16* __restrict__ Bk,
    const __bf16* __restrict__ Bv,
    const float* __restrict__ bq, const float* __restrict__ bk,
    const float* __restrict__ bv,
    __bf16* __restrict__ oq, __bf16* __restrict__ ok, __bf16* __restrict__ ov,
    const float* __restrict__ res, float* __restrict__ fout,
    int K, int mode)
{
  __shared__ __bf16 As[3 * 128 * 32];
  __shared__ __bf16 Bs[3 * 128 * 32];
  int tid = threadIdx.x;

  // chunked XCD swizzle (bijective; nwg % 8 == 0 for all our grids)
  int nwg = gridDim.x * gridDim.y;
  int cpx = nwg >> 3;
  int lid = blockIdx.x + gridDim.x * blockIdx.y;
  int logical = (lid & 7) * cpx + (lid >> 3);
  int bx = logical % gridDim.x;
  int by = logical / gridDim.x;
  int m0 = by * 128;
  int n0g = bx * 128;

  const __bf16* Bsel; const float* biassel; __bf16* osel; int ncol0;
  if (mode == 0) {
    int sel = n0g >> 9;
    Bsel = sel == 0 ? Bq : (sel == 1 ? Bk : Bv);
    biassel = sel == 0 ? bq : (sel == 1 ? bk : bv);
    osel = sel == 0 ? oq : (sel == 1 ? ok : ov);
    ncol0 = n0g & 511;
  } else {
    Bsel = Bq; biassel = bq; osel = oq; ncol0 = n0g;
  }

  int srow = tid >> 2;
  int scol = ((tid & 3) ^ ((srow >> 1) & 3)) * 8;   // pre-swizzled source slot
  int rg0 = m0 + srow;       if (rg0 > 9407) rg0 = 9407;
  int rg1 = m0 + 64 + srow;  if (rg1 > 9407) rg1 = 9407;
  const __bf16* a0 = A + (size_t)rg0 * K + scol;
  const __bf16* a1 = A + (size_t)rg1 * K + scol;
  const __bf16* b0 = Bsel + (size_t)(ncol0 + srow) * K + scol;
  const __bf16* b1 = Bsel + (size_t)(ncol0 + 64 + srow) * K + scol;
  char* sa0 = (char*)As + tid * 16;
  char* sa1 = (char*)As + 4096 + tid * 16;
  char* sb0 = (char*)Bs + tid * 16;
  char* sb1 = (char*)Bs + 4096 + tid * 16;

  int l = tid & 63, w = tid >> 6;
  int lm = l & 15, lq = l >> 4;
  int wm = w >> 1, wn = w & 1;
  int rsw = ((((lm >> 1) & 3) ^ lq)) * 8;          // swizzled read slot

  const int nsteps = K >> 5;
  // prologue: stage steps 0 and 1 into bufs 0 and 1
  async16(a0, sa0); async16(a1, sa1);
  async16(b0, sb0); async16(b1, sb1);
  async16(a0 + 32, sa0 + 8192); async16(a1 + 32, sa1 + 8192);
  async16(b0 + 32, sb0 + 8192); async16(b1 + 32, sb1 + 8192);
  __builtin_amdgcn_sched_barrier(0);
  asm volatile("s_waitcnt vmcnt(4)" ::: "memory");   // step-0 loads landed
  __builtin_amdgcn_s_barrier();
  __builtin_amdgcn_sched_barrier(0);

  ffrag4 acc[4][4] = {};
  int cur = 0;
  for (int t = 0; t < nsteps; ++t) {
    if (t + 2 < nsteps) {                 // issue depth-2 prefetch
      int k2 = (t + 2) << 5;
      int nb = cur + 2; if (nb >= 3) nb -= 3;
      int bo = nb * 8192;
      async16(a0 + k2, sa0 + bo); async16(a1 + k2, sa1 + bo);
      async16(b0 + k2, sb0 + bo); async16(b1 + k2, sb1 + bo);
    }
    int co = cur * 4096;
    bfrag8 af[4], bfr[4];
#pragma unroll
    for (int i = 0; i < 4; ++i)
      af[i] = *(const bfrag8*)&As[co + (wm * 64 + i * 16 + lm) * 32 + rsw];
#pragma unroll
    for (int j = 0; j < 4; ++j)
      bfr[j] = *(const bfrag8*)&Bs[co + (wn * 64 + j * 16 + lm) * 32 + rsw];
#pragma unroll
    for (int i = 0; i < 4; ++i)
#pragma unroll
      for (int j = 0; j < 4; ++j)
        acc[i][j] = __builtin_amdgcn_mfma_f32_16x16x32_bf16(af[i], bfr[j], acc[i][j], 0, 0, 0);
    __builtin_amdgcn_sched_barrier(0);
    if (t + 2 < nsteps) asm volatile("s_waitcnt vmcnt(4)" ::: "memory");
    else                asm volatile("s_waitcnt vmcnt(0)" ::: "memory");
    __builtin_amdgcn_s_barrier();
    __builtin_amdgcn_sched_barrier(0);
    cur += 1; if (cur == 3) cur = 0;
  }

#pragma unroll
  for (int i = 0; i < 4; ++i) {
    int mbase = m0 + wm * 64 + i * 16 + lq * 4;
#pragma unroll
    for (int j = 0; j < 4; ++j) {
      int n = ncol0 + wn * 64 + j * 16 + lm;
      float bj = biassel[n];
#pragma unroll
      for (int r = 0; r < 4; ++r) {
        int mr = mbase + r;
        if (mr < 9408) {
          float v = acc[i][j][r] + bj;
          if (mode == 0)      osel[(size_t)mr * 512 + n] = (__bf16)v;
          else if (mode == 1) osel[(size_t)mr * 1024 + n] = (__bf16)gelu_exact(v);
          else                fout[(size_t)mr * 512 + n] =
                                res[(size_t)mr * 512 + n] + gelu_exact(v);
        }
      }
    }
  }
}

// ------- temporal mixing as one flat NT GEMM: M=9408, N=512, K=6144 (u,d) ---
// z splits K 4-way; each z writes its OWN partial buffer with plain stores
// (NO atomics, no pre-zero). tc_epi sums the four partials.
// 128x128 tile, 3-buffer depth-2 pipeline with counted vmcnt, XCD swizzle.
__global__ __launch_bounds__(256) void mfma_tc_kernel(
    const __bf16* __restrict__ X2p, const __bf16* __restrict__ Wte,
    float* __restrict__ acc0, float* __restrict__ acc1,
    float* __restrict__ acc2, float* __restrict__ acc3)
{
  __shared__ __bf16 As[3 * 128 * 32];
  __shared__ __bf16 Bs[3 * 128 * 32];
  int tid = threadIdx.x;

  // grid (4,74,4) -> nwg=1184=8*148, chunked XCD swizzle
  int lid = blockIdx.x + 4 * (blockIdx.y + 74 * blockIdx.z);
  int logical = (lid & 7) * 148 + (lid >> 3);
  int lx = logical & 3;
  int rest = logical >> 2;         // ly + 74*lz
  int ly = rest % 74;
  int lz = rest / 74;

  int m0 = ly * 128;
  int n0 = lx * 128;
  int kbeg = lz * 1536;            // 48 K-steps per block
  float* accp = lz == 0 ? acc0 : (lz == 1 ? acc1 : (lz == 2 ? acc2 : acc3));

  int srow = tid >> 2;
  int scol = ((tid & 3) ^ ((srow >> 1) & 3)) * 8;
  int rg0 = m0 + srow;       if (rg0 > 9407) rg0 = 9407;
  int rg1 = m0 + 64 + srow;  if (rg1 > 9407) rg1 = 9407;
  int btq0 = rg0 / 196, p0_ = rg0 - btq0 * 196;
  int btq1 = rg1 / 196, p1_ = rg1 - btq1 * 196;
  const __bf16* a0 = X2p + (size_t)btq0 * 1204224 + (size_t)p0_ * 512 + scol;
  const __bf16* a1 = X2p + (size_t)btq1 * 1204224 + (size_t)p1_ * 512 + scol;
  const __bf16* b0 = Wte + (size_t)(n0 + srow) * 6144 + scol;
  const __bf16* b1 = Wte + (size_t)(n0 + 64 + srow) * 6144 + scol;
  char* sa0 = (char*)As + tid * 16;
  char* sa1 = (char*)As + 4096 + tid * 16;
  char* sb0 = (char*)Bs + tid * 16;
  char* sb1 = (char*)Bs + 4096 + tid * 16;

  int l = tid & 63, w = tid >> 6;
  int lm = l & 15, lq = l >> 4;
  int wm = w >> 1, wn = w & 1;
  int rsw = ((((lm >> 1) & 3) ^ lq)) * 8;

  // prologue: stage steps 0 and 1 into bufs 0 and 1
  {
    size_t ao0 = (size_t)(kbeg >> 9) * 100352 + (size_t)(kbeg & 511);
    int k1 = kbeg + 32;
    size_t ao1 = (size_t)(k1 >> 9) * 100352 + (size_t)(k1 & 511);
    async16(a0 + ao0, sa0); async16(a1 + ao0, sa1);
    async16(b0 + kbeg, sb0); async16(b1 + kbeg, sb1);
    async16(a0 + ao1, sa0 + 8192); async16(a1 + ao1, sa1 + 8192);
    async16(b0 + k1, sb0 + 8192); async16(b1 + k1, sb1 + 8192);
  }
  __builtin_amdgcn_sched_barrier(0);
  asm volatile("s_waitcnt vmcnt(4)" ::: "memory");
  __builtin_amdgcn_s_barrier();
  __builtin_amdgcn_sched_barrier(0);

  ffrag4 acc[4][4] = {};
  int cur = 0;
  for (int t = 0; t < 48; ++t) {
    if (t + 2 < 48) {
      int k2 = kbeg + (t + 2) * 32;
      size_t aoff = (size_t)(k2 >> 9) * 100352 + (size_t)(k2 & 511);
      int nb = cur + 2; if (nb >= 3) nb -= 3;
      int bo = nb * 8192;
      async16(a0 + aoff, sa0 + bo); async16(a1 + aoff, sa1 + bo);
      async16(b0 + k2, sb0 + bo); async16(b1 + k2, sb1 + bo);
    }
    int co = cur * 4096;
    bfrag8 af[4], bfr[4];
#pragma unroll
    for (int i = 0; i < 4; ++i)
      af[i] = *(const bfrag8*)&As[co + (wm * 64 + i * 16 + lm) * 32 + rsw];
#pragma unroll
    for (int j = 0; j < 4; ++j)
      bfr[j] = *(const bfrag8*)&Bs[co + (wn * 64 + j * 16 + lm) * 32 + rsw];
#pragma unroll
    for (int i = 0; i < 4; ++i)
#pragma unroll
      for (int j = 0; j < 4; ++j)
        acc[i][j] = __builtin_amdgcn_mfma_f32_16x16x32_bf16(af[i], bfr[j], acc[i][j], 0, 0, 0);
    __builtin_amdgcn_sched_barrier(0);
    if (t + 2 < 48) asm volatile("s_waitcnt vmcnt(4)" ::: "memory");
    else            asm volatile("s_waitcnt vmcnt(0)" ::: "memory");
    __builtin_amdgcn_s_barrier();
    __builtin_amdgcn_sched_barrier(0);
    cur += 1; if (cur == 3) cur = 0;
  }

#pragma unroll
  for (int i = 0; i < 4; ++i) {
    int mbase = m0 + wm * 64 + i * 16 + lq * 4;
#pragma unroll
    for (int j = 0; j < 4; ++j) {
      int n = n0 + wn * 64 + j * 16 + lm;
#pragma unroll
      for (int r = 0; r < 4; ++r) {
        int mr = mbase + r;
        if (mr < 9408)
          accp[(size_t)mr * 512 + n] = acc[i][j][r];
      }
    }
  }
}

// ------- tc epilogue + out-LN fused: xmid = x + gelu(sum(p)/12 + sbt); x3b = LN(xmid)
// NOTE: acc2 and xmid alias the same buffer (per-thread read-before-write at
// identical offsets) -> NO restrict on those two.
__global__ __launch_bounds__(64) void tc_epi_norm_kernel(
    const float* __restrict__ acc0, const float* __restrict__ acc1,
    const float* acc2, const float* __restrict__ acc3,
    const float* __restrict__ x, const float* __restrict__ sbt,
    const float* __restrict__ alpha, const float* __restrict__ beta,
    float* xmid, __bf16* __restrict__ x3b)
{
  size_t row = blockIdx.x;
  int l = threadIdx.x;
  size_t base = row * 512 + l * 8;
  float4 c0 = *(const float4*)(acc0 + base);
  float4 c1 = *(const float4*)(acc0 + base + 4);
  float4 d0 = *(const float4*)(acc1 + base);
  float4 d1 = *(const float4*)(acc1 + base + 4);
  float4 e0 = *(const float4*)(acc2 + base);
  float4 e1 = *(const float4*)(acc2 + base + 4);
  float4 g0 = *(const float4*)(acc3 + base);
  float4 g1 = *(const float4*)(acc3 + base + 4);
  float4 x0 = *(const float4*)(x + base);
  float4 x1 = *(const float4*)(x + base + 4);
  float4 s0 = *(const float4*)(sbt + l * 8);
  float4 s1 = *(const float4*)(sbt + l * 8 + 4);
  float cc[8] = {c0.x + d0.x + e0.x + g0.x, c0.y + d0.y + e0.y + g0.y,
                 c0.z + d0.z + e0.z + g0.z, c0.w + d0.w + e0.w + g0.w,
                 c1.x + d1.x + e1.x + g1.x, c1.y + d1.y + e1.y + g1.y,
                 c1.z + d1.z + e1.z + g1.z, c1.w + d1.w + e1.w + g1.w};
  float xx[8] = {x0.x, x0.y, x0.z, x0.w, x1.x, x1.y, x1.z, x1.w};
  float sv[8] = {s0.x, s0.y, s0.z, s0.w, s1.x, s1.y, s1.z, s1.w};
  float f[8];
#pragma unroll
  for (int q = 0; q < 8; ++q)
    f[q] = xx[q] + gelu_exact(cc[q] * (1.f / 12.f) + sv[q]);
  *(float4*)(xmid + base)     = make_float4(f[0], f[1], f[2], f[3]);
  *(float4*)(xmid + base + 4) = make_float4(f[4], f[5], f[6], f[7]);
  float s = 0.f, ss = 0.f;
#pragma unroll
  for (int q = 0; q < 8; ++q) { s += f[q]; ss += f[q] * f[q]; }
#pragma unroll
  for (int off = 32; off; off >>= 1) { s += __shfl_xor(s, off); ss += __shfl_xor(ss, off); }
  float mu = s * (1.f / 512.f);
  float var = fmaxf((ss - 512.f * mu * mu) * (1.f / 511.f), 0.f);
  float inv = 1.f / (sqrtf(var) + EPS);
  const float* al = alpha + l * 8;
  const float* be = beta + l * 8;
  float4 a0 = *(const float4*)al, a1 = *(const float4*)(al + 4);
  float4 b0 = *(const float4*)be, b1 = *(const float4*)(be + 4);
  float aa[8] = {a0.x, a0.y, a0.z, a0.w, a1.x, a1.y, a1.z, a1.w};
  float bb[8] = {b0.x, b0.y, b0.z, b0.w, b1.x, b1.y, b1.z, b1.w};
  bfrag8 o;
#pragma unroll
  for (int q = 0; q < 8; ++q) o[q] = (__bf16)(aa[q] * (f[q] - mu) * inv + bb[q]);
  *(bfrag8*)(x3b + base) = o;
}

// ------------- MFMA attention v3: 32x32x16, S^T route, no-max softmax,
// in-register P via cvt_pk + permlane32_swap (no P LDS round-trip) ----------
__global__ __launch_bounds__(512, 4) void attn_kernel(
    const __bf16* __restrict__ Q, const __bf16* __restrict__ K,
    const __bf16* __restrict__ V, __bf16* __restrict__ av)
{
  __shared__ __bf16 Ks[196 * 64];
  __shared__ __bf16 Vt[64 * 208];

  int bid = blockIdx.x;
  int half = bid & 1;
  int h = (bid >> 1) & 7;
  int r0 = bid >> 4;               // 0..47
  int u = r0 % 12;
  int b = r0 / 12;

  const __bf16* Kp = K + ((size_t)(b * 12 + u) * 196) * 512 + h * 64;
  const __bf16* Vp = V + ((size_t)(b * 12 + u) * 196) * 512 + h * 64;

  for (int idx = threadIdx.x; idx < 196 * 8; idx += 512) {
    int r = idx >> 3, g = idx & 7;
    *(bfrag8*)&Ks[r * 64 + ((g ^ (r & 7)) * 8)] =
        *(const bfrag8*)&Kp[(size_t)r * 512 + g * 8];
  }
  for (int idx = threadIdx.x; idx < 64 * 6; idx += 512) {
    int r = idx / 6, c2 = 196 + (idx % 6) * 2;
    bf16p2 z; z.v[0] = (__bf16)0.f; z.v[1] = (__bf16)0.f;
    *(bf16p2*)&Vt[r * 208 + c2] = z;
  }
  for (int idx = threadIdx.x; idx < 98 * 8; idx += 512) {
    int r2 = (idx % 98) * 2, c8 = (idx / 98) * 8;
    bfrag8 va = *(const bfrag8*)&Vp[(size_t)r2 * 512 + c8];
    bfrag8 vb = *(const bfrag8*)&Vp[(size_t)(r2 + 1) * 512 + c8];
#pragma unroll
    for (int e = 0; e < 8; ++e) {
      bf16p2 pr; pr.v[0] = va[e]; pr.v[1] = vb[e];
      *(bf16p2*)&Vt[(c8 + e) * 208 + r2] = pr;
    }
  }
  __syncthreads();

  int w = threadIdx.x >> 6, l = threadIdx.x & 63;
  int l5 = l >> 5, c = l & 31;

  for (int unit = w; unit < 42; unit += 8) {
    int t = unit / 7, qt = unit - t * 7;
    int tq = half * 6 + t;
    const __bf16* Qp = Q + ((size_t)(b * 12 + tq) * 196) * 512 + h * 64;
    __bf16* avp = av + ((size_t)((b * 12 + tq) * 12 + u) * 196) * 512 + h * 64;
    int q0 = qt * 32;

    const __bf16* qp = Qp + (size_t)(q0 + c) * 512 + l5 * 8;
    bfrag8 qf[4];
    qf[0] = *(const bfrag8*)(qp);
    qf[1] = *(const bfrag8*)(qp + 16);
    qf[2] = *(const bfrag8*)(qp + 32);
    qf[3] = *(const bfrag8*)(qp + 48);

    ffrag16 O0, O1;
#pragma unroll
    for (int g = 0; g < 16; ++g) { O0[g] = 0.f; O1[g] = 0.f; }
    float sumacc = 0.f;

    // main loop: nt = 0..5, keys 0..191 (no boundary mask needed)
    for (int nt = 0; nt < 6; ++nt) {
      int key = nt * 32 + c;
      const __bf16* kbase = &Ks[key * 64];
      int kx = key & 7;

      ffrag16 s;
#pragma unroll
      for (int g = 0; g < 16; ++g) s[g] = 0.f;
#pragma unroll
      for (int kc = 0; kc < 4; ++kc) {
        bfrag8 kf = *(const bfrag8*)&kbase[(((kc * 2 + l5) ^ kx) * 8)];
        s = __builtin_amdgcn_mfma_f32_32x32x16_bf16(kf, qf[kc], s, 0, 0, 0);
      }

#pragma unroll
      for (int g = 0; g < 16; ++g) {
        float e = __expf(s[g] * 0.125f);
        s[g] = e;
        sumacc += e;
      }

#pragma unroll
      for (int sub = 0; sub < 2; ++sub) {
        int A0 = cvt_pk_bf16(s[sub * 8 + 0], s[sub * 8 + 1]);
        int A1 = cvt_pk_bf16(s[sub * 8 + 2], s[sub * 8 + 3]);
        int A2 = cvt_pk_bf16(s[sub * 8 + 4], s[sub * 8 + 5]);
        int A3 = cvt_pk_bf16(s[sub * 8 + 6], s[sub * 8 + 7]);
        perm_swap(A0, A2);   // A0 = word0 (k 0,1 | 8,9), A2 = word2 (k 4,5 | 12,13)
        perm_swap(A1, A3);   // A1 = word1, A3 = word3
        union { int i[4]; bfrag8 v; } pu;
        pu.i[0] = A0; pu.i[1] = A1; pu.i[2] = A2; pu.i[3] = A3;
        bfrag8 pa = pu.v;
        int ch = nt * 2 + sub;
        bfrag8 v0 = *(const bfrag8*)&Vt[(size_t)(c     ) * 208 + ch * 16 + l5 * 8];
        bfrag8 v1 = *(const bfrag8*)&Vt[(size_t)(c + 32) * 208 + ch * 16 + l5 * 8];
        O0 = __builtin_amdgcn_mfma_f32_32x32x16_bf16(pa, v0, O0, 0, 0, 0);
        O1 = __builtin_amdgcn_mfma_f32_32x32x16_bf16(pa, v1, O1, 0, 0, 0);
      }
    }

    // tail: nt = 6, keys 192..195 valid, one 16-key chunk
    {
      int key = 192 + c; if (key > 195) key = 195;
      const __bf16* kbase = &Ks[key * 64];
      int kx = key & 7;

      ffrag16 s;
#pragma unroll
      for (int g = 0; g < 16; ++g) s[g] = 0.f;
#pragma unroll
      for (int kc = 0; kc < 4; ++kc) {
        bfrag8 kf = *(const bfrag8*)&kbase[(((kc * 2 + l5) ^ kx) * 8)];
        s = __builtin_amdgcn_mfma_f32_32x32x16_bf16(kf, qf[kc], s, 0, 0, 0);
      }
#pragma unroll
      for (int g = 0; g < 16; ++g) {
        float e = __expf(s[g] * 0.125f);
        bool keep = (g < 4) && (l5 == 0);
        e = keep ? e : 0.f;
        s[g] = e;
        sumacc += e;
      }
      int A0 = cvt_pk_bf16(s[0], s[1]);
      int A1 = cvt_pk_bf16(s[2], s[3]);
      int A2 = cvt_pk_bf16(s[4], s[5]);
      int A3 = cvt_pk_bf16(s[6], s[7]);
      perm_swap(A0, A2);
      perm_swap(A1, A3);
      union { int i[4]; bfrag8 v; } pu;
      pu.i[0] = A0; pu.i[1] = A1; pu.i[2] = A2; pu.i[3] = A3;
      bfrag8 pa = pu.v;
      bfrag8 v0 = *(const bfrag8*)&Vt[(size_t)(c     ) * 208 + 12 * 16 + l5 * 8];
      bfrag8 v1 = *(const bfrag8*)&Vt[(size_t)(c + 32) * 208 + 12 * 16 + l5 * 8];
      O0 = __builtin_amdgcn_mfma_f32_32x32x16_bf16(pa, v0, O0, 0, 0, 0);
      O1 = __builtin_amdgcn_mfma_f32_32x32x16_bf16(pa, v1, O1, 0, 0, 0);
    }

    float stot = sumacc + __shfl_xor(sumacc, 32);

#pragma unroll
    for (int g = 0; g < 16; ++g) {
      int row = (g & 3) + 8 * (g >> 2) + 4 * l5;
      float sq = __shfl(stot, row);
      float iv = __builtin_amdgcn_rcpf(sq);
      int q = q0 + row;
      if (q < 196) {
        size_t base = (size_t)q * 512 + c;
        avp[base]      = (__bf16)(O0[g] * iv);
        avp[base + 32] = (__bf16)(O1[g] * iv);
      }
    }
  }
}

extern "C" void kernel_launch(void* const* d_in, const int* in_sizes, int n_in,
                              void* d_out, int out_size, void* d_ws, size_t ws_size,
                              hipStream_t stream)
{
  const float* x      = (const float*)d_in[0];
  const float* Wq     = (const float*)d_in[1];
  const float* bq     = (const float*)d_in[2];
  const float* Wk     = (const float*)d_in[3];
  const float* bk     = (const float*)d_in[4];
  const float* Wv     = (const float*)d_in[5];
  const float* bv     = (const float*)d_in[6];
  const float* in_a   = (const float*)d_in[7];
  const float* in_b   = (const float*)d_in[8];
  const float* attn_a = (const float*)d_in[9];
  const float* attn_b = (const float*)d_in[10];
  const float* out_a  = (const float*)d_in[11];
  const float* out_b  = (const float*)d_in[12];
  const float* Wt     = (const float*)d_in[13];
  const float* bt     = (const float*)d_in[14];
  const float* pos    = (const float*)d_in[15];
  const float* W1     = (const float*)d_in[16];
  const float* b1     = (const float*)d_in[17];
  const float* W2     = (const float*)d_in[18];
  const float* b2     = (const float*)d_in[19];

  char* ws = (char*)d_ws;
  const size_t bfb = (size_t)9408 * 512 * 2;       // 9,633,792 B (bf16 MxD)
  __bf16* x2b  = (__bf16*)(ws);
  __bf16* Qb   = (__bf16*)(ws + bfb);
  __bf16* Kb   = (__bf16*)(ws + 2 * bfb);
  __bf16* Vb   = (__bf16*)(ws + 3 * bfb);
  __bf16* av   = (__bf16*)(ws + 4 * bfb);          // 115,605,504 B
  char*   wreg = ws + 4 * bfb + (size_t)115605504; // weights bf16, 9,961,472 B
  __bf16* Wqb  = (__bf16*)(wreg);
  __bf16* Wkb  = (__bf16*)(wreg) + 262144;
  __bf16* Wvb  = (__bf16*)(wreg) + 524288;
  __bf16* W1b  = (__bf16*)(wreg) + 786432;
  __bf16* W2b  = (__bf16*)(wreg) + 1310720;
  __bf16* Wtb  = (__bf16*)(wreg) + 1835008;        // transposed [e][u*512+d]
  float*  sbt  = (float*)(wreg + 9961472);
  float*  acc0 = (float*)(wreg + 9963520);         // 19,267,584 B partial z=0
  // overlays (stream-ordered lifetimes):
  float*  acc1 = (float*)(ws + 2 * bfb);           // over Kb+Vb (dead after attn)
  float*  acc2 = (float*)(ws);                     // over x2b+Qb (dead after attn); same addrs as xmid
  float*  acc3 = (float*)d_out;                    // d_out fully overwritten by MLP2
  float*  xmid = (float*)(ws);                     // over x2b+Qb (aliases acc2; epi reads-then-writes)
  __bf16* x3b  = (__bf16*)(ws + 4 * bfb + 33554432); // in av slab (dead after tc); hb uses first 19.3MB
  __bf16* hb   = (__bf16*)(ws + 4 * bfb);          // over av[0..19.3MB)
  float*  out  = (float*)d_out;

  conv_w_kernel<<<2432, 256, 0, stream>>>(Wq, Wk, Wv, W1, W2, Wt, (__bf16*)wreg);
  sum_bt_kernel<<<1, 512, 0, stream>>>(bt, sbt);
  norm_f32_to_bf16_kernel<<<9408, 64, 0, stream>>>(x, x2b, in_a, in_b);
  mfma_nt_kernel<<<dim3(12, 74), 256, 0, stream>>>(
      x2b, Wqb, Wkb, Wvb, bq, bk, bv, Qb, Kb, Vb, nullptr, nullptr, 512, 0);
  attn_kernel<<<768, 512, 0, stream>>>(Qb, Kb, Vb, av);
  norm_av_kernel<<<28224, 256, 0, stream>>>((bf16*)av, attn_a, attn_b, pos);
  mfma_tc_kernel<<<dim3(4, 74, 4), 256, 0, stream>>>(av, Wtb, acc0, acc1, acc2, acc3);
  tc_epi_norm_kernel<<<9408, 64, 0, stream>>>(
      acc0, acc1, acc2, acc3, x, sbt, out_a, out_b, xmid, x3b);
  mfma_nt_kernel<<<dim3(8, 74), 256, 0, stream>>>(
      x3b, W1b, nullptr, nullptr, b1, nullptr, nullptr, hb, nullptr, nullptr,
      nullptr, nullptr, 512, 1);
  mfma_nt_kernel<<<dim3(4, 74), 256, 0, stream>>>(
      hb, W2b, nullptr, nullptr, b2, nullptr, nullptr, nullptr, nullptr, nullptr,
      xmid, out, 1024, 2);
}

// Round 7
// 469.037 us; speedup vs baseline: 1.1177x; 1.1177x over previous
//
#include <hip/hip_runtime.h>
#include <hip/hip_bf16.h>

typedef __hip_bfloat16 bf16;

typedef __bf16 bfrag8 __attribute__((ext_vector_type(8)));
typedef __bf16 bfrag4 __attribute__((ext_vector_type(4)));
typedef float  ffrag4 __attribute__((ext_vector_type(4)));
typedef float  ffrag16 __attribute__((ext_vector_type(16)));

// B=4, T=12, P=196, D=512, H=8, DH=64 ; M = B*T*P = 9408 = 73.5*128
#define EPS 1e-6f

__device__ __forceinline__ float gelu_exact(float v) {
  return 0.5f * v * (1.0f + erff(v * 0.7071067811865475f));
}

__device__ __forceinline__ void async16(const void* g, void* s) {
  __builtin_amdgcn_global_load_lds(
      (const __attribute__((address_space(1))) unsigned int*)g,
      (__attribute__((address_space(3))) unsigned int*)s, 16, 0, 0);
}

// pack two f32 -> one dword of 2 bf16 (lo = a, hi = b)
__device__ __forceinline__ int cvt_pk_bf16(float a, float b) {
  int r;
  asm("v_cvt_pk_bf16_f32 %0, %1, %2" : "=v"(r) : "v"(a), "v"(b));
  return r;
}
// vdst.hi32lanes <-> vsrc.lo32lanes
__device__ __forceinline__ void perm_swap(int& a, int& b) {
  asm volatile("v_permlane32_swap_b32 %0, %1" : "+v"(a), "+v"(b));
}

struct alignas(16) bf16x8 { bf16 v[8]; };
struct alignas(4)  bf16p2 { __bf16 v[2]; };

// ---------------- weight convert f32 -> bf16, packed region ----------------
// Wt is transposed [u][e][d] -> [e][u][d] so tc's B-rows are contiguous (K=6144)
__global__ __launch_bounds__(256) void conv_w_kernel(
    const float* __restrict__ Wq, const float* __restrict__ Wk,
    const float* __restrict__ Wv, const float* __restrict__ W1,
    const float* __restrict__ W2, const float* __restrict__ Wt,
    __bf16* __restrict__ dst)
{
  size_t e = ((size_t)blockIdx.x * 256 + threadIdx.x) * 8;
  const float* src; size_t off, dsto;
  if      (e <  262144) { src = Wq; off = e;           dsto = e; }
  else if (e <  524288) { src = Wk; off = e -  262144; dsto = e; }
  else if (e <  786432) { src = Wv; off = e -  524288; dsto = e; }
  else if (e < 1310720) { src = W1; off = e -  786432; dsto = e; }
  else if (e < 1835008) { src = W2; off = e - 1310720; dsto = e; }
  else if (e < 4980736) {
    src = Wt; off = e - 1835008;
    size_t u = off >> 18;            // / (512*512)
    size_t rem = off & 262143;
    size_t eo = rem >> 9, d = rem & 511;
    dsto = 1835008 + eo * 6144 + u * 512 + d;   // [e][u*512+d]
  }
  else return;
  float4 f0 = *(const float4*)(src + off);
  float4 f1 = *(const float4*)(src + off + 4);
  bfrag8 o;
  o[0] = (__bf16)f0.x; o[1] = (__bf16)f0.y; o[2] = (__bf16)f0.z; o[3] = (__bf16)f0.w;
  o[4] = (__bf16)f1.x; o[5] = (__bf16)f1.y; o[6] = (__bf16)f1.z; o[7] = (__bf16)f1.w;
  *(bfrag8*)(dst + dsto) = o;
}

__global__ __launch_bounds__(512) void sum_bt_kernel(
    const float* __restrict__ bt, float* __restrict__ sbt)
{
  int n = threadIdx.x;
  float s = 0.f;
#pragma unroll
  for (int u = 0; u < 12; ++u) s += bt[u * 512 + n];
  sbt[n] = s;
}

// ------------- LayerNorm f32 -> bf16, one 64-thread block per row of 512 ----
__global__ __launch_bounds__(64) void norm_f32_to_bf16_kernel(
    const float* __restrict__ in, __bf16* __restrict__ out,
    const float* __restrict__ alpha, const float* __restrict__ beta)
{
  size_t row = blockIdx.x;
  int l = threadIdx.x;
  const float* r = in + row * 512 + l * 8;
  float4 v0 = *(const float4*)(r);
  float4 v1 = *(const float4*)(r + 4);
  float f[8] = {v0.x, v0.y, v0.z, v0.w, v1.x, v1.y, v1.z, v1.w};
  float s = 0.f, ss = 0.f;
#pragma unroll
  for (int q = 0; q < 8; ++q) { s += f[q]; ss += f[q] * f[q]; }
#pragma unroll
  for (int off = 32; off; off >>= 1) { s += __shfl_xor(s, off); ss += __shfl_xor(ss, off); }
  float mu = s * (1.f / 512.f);
  float var = fmaxf((ss - 512.f * mu * mu) * (1.f / 511.f), 0.f);
  float inv = 1.f / (sqrtf(var) + EPS);
  const float* al = alpha + l * 8;
  const float* be = beta + l * 8;
  float4 a0 = *(const float4*)al, a1 = *(const float4*)(al + 4);
  float4 b0 = *(const float4*)be, b1 = *(const float4*)(be + 4);
  float aa[8] = {a0.x, a0.y, a0.z, a0.w, a1.x, a1.y, a1.z, a1.w};
  float bb[8] = {b0.x, b0.y, b0.z, b0.w, b1.x, b1.y, b1.z, b1.w};
  bfrag8 o;
#pragma unroll
  for (int q = 0; q < 8; ++q) o[q] = (__bf16)(aa[q] * (f[q] - mu) * inv + bb[q]);
  *(bfrag8*)(out + row * 512 + l * 8) = o;
}

// ------------- LayerNorm bf16 in-place + pos add; 4 rows per 256-thr block --
__global__ __launch_bounds__(256) void norm_av_kernel(
    bf16* __restrict__ av, const float* __restrict__ alpha,
    const float* __restrict__ beta, const float* __restrict__ pos)
{
  size_t row = (size_t)blockIdx.x * 4 + (threadIdx.x >> 6);  // [0, B*T*T*P)
  int l = threadIdx.x & 63;
  bf16* r = av + row * 512 + (size_t)l * 8;
  bf16x8 ib = *(const bf16x8*)r;
  float f[8];
#pragma unroll
  for (int q = 0; q < 8; ++q) f[q] = __bfloat162float(ib.v[q]);
  float s = 0.f, ss = 0.f;
#pragma unroll
  for (int q = 0; q < 8; ++q) { s += f[q]; ss += f[q] * f[q]; }
#pragma unroll
  for (int off = 32; off; off >>= 1) { s += __shfl_xor(s, off); ss += __shfl_xor(ss, off); }
  float mu = s * (1.f / 512.f);
  float var = fmaxf((ss - 512.f * mu * mu) * (1.f / 511.f), 0.f);
  float inv = 1.f / (sqrtf(var) + EPS);
  size_t prow = row % 28224;        // T*T*P  (pos broadcasts over batch)
  const float* pr = pos + prow * 512 + l * 8;
  float4 p0 = *(const float4*)pr, p1 = *(const float4*)(pr + 4);
  const float* al = alpha + l * 8;
  const float* be = beta + l * 8;
  float4 a0 = *(const float4*)al, a1 = *(const float4*)(al + 4);
  float4 b0 = *(const float4*)be, b1 = *(const float4*)(be + 4);
  float pa[8] = {p0.x, p0.y, p0.z, p0.w, p1.x, p1.y, p1.z, p1.w};
  float aa[8] = {a0.x, a0.y, a0.z, a0.w, a1.x, a1.y, a1.z, a1.w};
  float bb[8] = {b0.x, b0.y, b0.z, b0.w, b1.x, b1.y, b1.z, b1.w};
  bf16x8 ob;
#pragma unroll
  for (int q = 0; q < 8; ++q)
    ob.v[q] = __float2bfloat16(aa[q] * (f[q] - mu) * inv + bb[q] + pa[q]);
  *(bf16x8*)r = ob;
}

// ------------- MFMA NT GEMM, 128x128 tile, BK=32, 3-buffer pipeline ---------
// 512 threads / 8 waves, each wave a 32x64 sub-tile (2x4 frags, 8 MFMA/step)
// -> 6 waves/SIMD resident (3 blocks/CU) to hide ds_read + barrier stalls.
// Depth-2 prefetch, ONE raw barrier per K-step, counted vmcnt(2).
// LDS slot swizzle on both sides. Chunked XCD swizzle.
// mode 0: fused QKV (N=1536), out bf16 +bias; mode 1: MLP1, out bf16 gelu;
// mode 2: MLP2, out f32 = res + gelu(acc+bias)
__global__ __launch_bounds__(512) void mfma_nt_kernel(
    const __bf16* __restrict__ A,
    const __bf16* __restrict__ Bq, const __bf16* __restrict__ Bk,
    const __bf16* __restrict__ Bv,
    const float* __restrict__ bq, const float* __restrict__ bk,
    const float* __restrict__ bv,
    __bf16* __restrict__ oq, __bf16* __restrict__ ok, __bf16* __restrict__ ov,
    const float* __restrict__ res, float* __restrict__ fout,
    int K, int mode)
{
  __shared__ __bf16 As[3 * 128 * 32];
  __shared__ __bf16 Bs[3 * 128 * 32];
  int tid = threadIdx.x;

  // chunked XCD swizzle (bijective; nwg % 8 == 0 for all our grids)
  int nwg = gridDim.x * gridDim.y;
  int cpx = nwg >> 3;
  int lid = blockIdx.x + gridDim.x * blockIdx.y;
  int logical = (lid & 7) * cpx + (lid >> 3);
  int bx = logical % gridDim.x;
  int by = logical / gridDim.x;
  int m0 = by * 128;
  int n0g = bx * 128;

  const __bf16* Bsel; const float* biassel; __bf16* osel; int ncol0;
  if (mode == 0) {
    int sel = n0g >> 9;
    Bsel = sel == 0 ? Bq : (sel == 1 ? Bk : Bv);
    biassel = sel == 0 ? bq : (sel == 1 ? bk : bv);
    osel = sel == 0 ? oq : (sel == 1 ? ok : ov);
    ncol0 = n0g & 511;
  } else {
    Bsel = Bq; biassel = bq; osel = oq; ncol0 = n0g;
  }

  int srow = tid >> 2;                              // 0..127
  int scol = ((tid & 3) ^ ((srow >> 1) & 3)) * 8;   // pre-swizzled source slot
  int rg0 = m0 + srow;       if (rg0 > 9407) rg0 = 9407;
  const __bf16* a0 = A + (size_t)rg0 * K + scol;
  const __bf16* b0 = Bsel + (size_t)(ncol0 + srow) * K + scol;
  char* sa0 = (char*)As + tid * 16;
  char* sb0 = (char*)Bs + tid * 16;

  int l = tid & 63, w = tid >> 6;                   // 8 waves
  int lm = l & 15, lq = l >> 4;
  int wm = w >> 1, wn = w & 1;                      // 4x2 wave grid, 32x64 each
  int rsw = ((((lm >> 1) & 3) ^ lq)) * 8;           // swizzled read slot

  const int nsteps = K >> 5;
  // prologue: stage steps 0 and 1 into bufs 0 and 1 (one async16 per panel)
  async16(a0, sa0); async16(b0, sb0);
  async16(a0 + 32, sa0 + 8192); async16(b0 + 32, sb0 + 8192);
  __builtin_amdgcn_sched_barrier(0);
  asm volatile("s_waitcnt vmcnt(2)" ::: "memory");   // step-0 loads landed
  __builtin_amdgcn_s_barrier();
  __builtin_amdgcn_sched_barrier(0);

  ffrag4 acc[2][4] = {};
  int cur = 0;
  for (int t = 0; t < nsteps; ++t) {
    if (t + 2 < nsteps) {                 // issue depth-2 prefetch
      int k2 = (t + 2) << 5;
      int nb = cur + 2; if (nb >= 3) nb -= 3;
      int bo = nb * 8192;
      async16(a0 + k2, sa0 + bo); async16(b0 + k2, sb0 + bo);
    }
    int co = cur * 4096;
    bfrag8 af[2], bfr[4];
#pragma unroll
    for (int i = 0; i < 2; ++i)
      af[i] = *(const bfrag8*)&As[co + (wm * 32 + i * 16 + lm) * 32 + rsw];
#pragma unroll
    for (int j = 0; j < 4; ++j)
      bfr[j] = *(const bfrag8*)&Bs[co + (wn * 64 + j * 16 + lm) * 32 + rsw];
#pragma unroll
    for (int i = 0; i < 2; ++i)
#pragma unroll
      for (int j = 0; j < 4; ++j)
        acc[i][j] = __builtin_amdgcn_mfma_f32_16x16x32_bf16(af[i], bfr[j], acc[i][j], 0, 0, 0);
    __builtin_amdgcn_sched_barrier(0);
    if (t + 2 < nsteps) asm volatile("s_waitcnt vmcnt(2)" ::: "memory");
    else                asm volatile("s_waitcnt vmcnt(0)" ::: "memory");
    __builtin_amdgcn_s_barrier();
    __builtin_amdgcn_sched_barrier(0);
    cur += 1; if (cur == 3) cur = 0;
  }

#pragma unroll
  for (int i = 0; i < 2; ++i) {
    int mbase = m0 + wm * 32 + i * 16 + lq * 4;
#pragma unroll
    for (int j = 0; j < 4; ++j) {
      int n = ncol0 + wn * 64 + j * 16 + lm;
      float bj = biassel[n];
#pragma unroll
      for (int r = 0; r < 4; ++r) {
        int mr = mbase + r;
        if (mr < 9408) {
          float v = acc[i][j][r] + bj;
          if (mode == 0)      osel[(size_t)mr * 512 + n] = (__bf16)v;
          else if (mode == 1) osel[(size_t)mr * 1024 + n] = (__bf16)gelu_exact(v);
          else                fout[(size_t)mr * 512 + n] =
                                res[(size_t)mr * 512 + n] + gelu_exact(v);
        }
      }
    }
  }
}

// ------- temporal mixing as one flat NT GEMM: M=9408, N=512, K=6144 (u,d) ---
// z splits K 2-way; each z writes its OWN partial buffer with plain stores
// (NO atomics, no pre-zero). tc_epi sums the two partials.
// 512 threads / 8 waves / 32x64 sub-tiles; 3-buffer depth-2 counted-vmcnt
// pipeline; chunked XCD swizzle.
__global__ __launch_bounds__(512) void mfma_tc_kernel(
    const __bf16* __restrict__ X2p, const __bf16* __restrict__ Wte,
    float* __restrict__ acc0, float* __restrict__ acc1)
{
  __shared__ __bf16 As[3 * 128 * 32];
  __shared__ __bf16 Bs[3 * 128 * 32];
  int tid = threadIdx.x;

  // grid (4,74,2) -> nwg=592=8*74, chunked XCD swizzle
  int lid = blockIdx.x + 4 * (blockIdx.y + 74 * blockIdx.z);
  int logical = (lid & 7) * 74 + (lid >> 3);
  int lx = logical & 3;
  int rest = logical >> 2;         // ly + 74*lz
  int ly = rest % 74;
  int lz = rest / 74;

  int m0 = ly * 128;
  int n0 = lx * 128;
  int kbeg = lz * 3072;            // 96 K-steps per block
  float* accp = lz == 0 ? acc0 : acc1;

  int srow = tid >> 2;             // 0..127
  int scol = ((tid & 3) ^ ((srow >> 1) & 3)) * 8;
  int rg0 = m0 + srow;       if (rg0 > 9407) rg0 = 9407;
  int btq0 = rg0 / 196, p0_ = rg0 - btq0 * 196;
  const __bf16* a0 = X2p + (size_t)btq0 * 1204224 + (size_t)p0_ * 512 + scol;
  const __bf16* b0 = Wte + (size_t)(n0 + srow) * 6144 + scol;
  char* sa0 = (char*)As + tid * 16;
  char* sb0 = (char*)Bs + tid * 16;

  int l = tid & 63, w = tid >> 6;
  int lm = l & 15, lq = l >> 4;
  int wm = w >> 1, wn = w & 1;
  int rsw = ((((lm >> 1) & 3) ^ lq)) * 8;

  // prologue: stage steps 0 and 1 into bufs 0 and 1
  {
    size_t ao0 = (size_t)(kbeg >> 9) * 100352 + (size_t)(kbeg & 511);
    int k1 = kbeg + 32;
    size_t ao1 = (size_t)(k1 >> 9) * 100352 + (size_t)(k1 & 511);
    async16(a0 + ao0, sa0); async16(b0 + kbeg, sb0);
    async16(a0 + ao1, sa0 + 8192); async16(b0 + k1, sb0 + 8192);
  }
  __builtin_amdgcn_sched_barrier(0);
  asm volatile("s_waitcnt vmcnt(2)" ::: "memory");
  __builtin_amdgcn_s_barrier();
  __builtin_amdgcn_sched_barrier(0);

  ffrag4 acc[2][4] = {};
  int cur = 0;
  for (int t = 0; t < 96; ++t) {
    if (t + 2 < 96) {
      int k2 = kbeg + (t + 2) * 32;
      size_t aoff = (size_t)(k2 >> 9) * 100352 + (size_t)(k2 & 511);
      int nb = cur + 2; if (nb >= 3) nb -= 3;
      int bo = nb * 8192;
      async16(a0 + aoff, sa0 + bo); async16(b0 + k2, sb0 + bo);
    }
    int co = cur * 4096;
    bfrag8 af[2], bfr[4];
#pragma unroll
    for (int i = 0; i < 2; ++i)
      af[i] = *(const bfrag8*)&As[co + (wm * 32 + i * 16 + lm) * 32 + rsw];
#pragma unroll
    for (int j = 0; j < 4; ++j)
      bfr[j] = *(const bfrag8*)&Bs[co + (wn * 64 + j * 16 + lm) * 32 + rsw];
#pragma unroll
    for (int i = 0; i < 2; ++i)
#pragma unroll
      for (int j = 0; j < 4; ++j)
        acc[i][j] = __builtin_amdgcn_mfma_f32_16x16x32_bf16(af[i], bfr[j], acc[i][j], 0, 0, 0);
    __builtin_amdgcn_sched_barrier(0);
    if (t + 2 < 96) asm volatile("s_waitcnt vmcnt(2)" ::: "memory");
    else            asm volatile("s_waitcnt vmcnt(0)" ::: "memory");
    __builtin_amdgcn_s_barrier();
    __builtin_amdgcn_sched_barrier(0);
    cur += 1; if (cur == 3) cur = 0;
  }

#pragma unroll
  for (int i = 0; i < 2; ++i) {
    int mbase = m0 + wm * 32 + i * 16 + lq * 4;
#pragma unroll
    for (int j = 0; j < 4; ++j) {
      int n = n0 + wn * 64 + j * 16 + lm;
#pragma unroll
      for (int r = 0; r < 4; ++r) {
        int mr = mbase + r;
        if (mr < 9408)
          accp[(size_t)mr * 512 + n] = acc[i][j][r];
      }
    }
  }
}

// ------- tc epilogue + out-LN fused: xmid = x + gelu((p0+p1)/12 + sbt); x3b = LN(xmid)
__global__ __launch_bounds__(64) void tc_epi_norm_kernel(
    const float* __restrict__ acc0, const float* __restrict__ acc1,
    const float* __restrict__ x, const float* __restrict__ sbt,
    const float* __restrict__ alpha, const float* __restrict__ beta,
    float* __restrict__ xmid, __bf16* __restrict__ x3b)
{
  size_t row = blockIdx.x;
  int l = threadIdx.x;
  size_t base = row * 512 + l * 8;
  float4 c0 = *(const float4*)(acc0 + base);
  float4 c1 = *(const float4*)(acc0 + base + 4);
  float4 d0 = *(const float4*)(acc1 + base);
  float4 d1 = *(const float4*)(acc1 + base + 4);
  float4 x0 = *(const float4*)(x + base);
  float4 x1 = *(const float4*)(x + base + 4);
  float4 s0 = *(const float4*)(sbt + l * 8);
  float4 s1 = *(const float4*)(sbt + l * 8 + 4);
  float cc[8] = {c0.x + d0.x, c0.y + d0.y, c0.z + d0.z, c0.w + d0.w,
                 c1.x + d1.x, c1.y + d1.y, c1.z + d1.z, c1.w + d1.w};
  float xx[8] = {x0.x, x0.y, x0.z, x0.w, x1.x, x1.y, x1.z, x1.w};
  float sv[8] = {s0.x, s0.y, s0.z, s0.w, s1.x, s1.y, s1.z, s1.w};
  float f[8];
#pragma unroll
  for (int q = 0; q < 8; ++q)
    f[q] = xx[q] + gelu_exact(cc[q] * (1.f / 12.f) + sv[q]);
  *(float4*)(xmid + base)     = make_float4(f[0], f[1], f[2], f[3]);
  *(float4*)(xmid + base + 4) = make_float4(f[4], f[5], f[6], f[7]);
  float s = 0.f, ss = 0.f;
#pragma unroll
  for (int q = 0; q < 8; ++q) { s += f[q]; ss += f[q] * f[q]; }
#pragma unroll
  for (int off = 32; off; off >>= 1) { s += __shfl_xor(s, off); ss += __shfl_xor(ss, off); }
  float mu = s * (1.f / 512.f);
  float var = fmaxf((ss - 512.f * mu * mu) * (1.f / 511.f), 0.f);
  float inv = 1.f / (sqrtf(var) + EPS);
  const float* al = alpha + l * 8;
  const float* be = beta + l * 8;
  float4 a0 = *(const float4*)al, a1 = *(const float4*)(al + 4);
  float4 b0 = *(const float4*)be, b1 = *(const float4*)(be + 4);
  float aa[8] = {a0.x, a0.y, a0.z, a0.w, a1.x, a1.y, a1.z, a1.w};
  float bb[8] = {b0.x, b0.y, b0.z, b0.w, b1.x, b1.y, b1.z, b1.w};
  bfrag8 o;
#pragma unroll
  for (int q = 0; q < 8; ++q) o[q] = (__bf16)(aa[q] * (f[q] - mu) * inv + bb[q]);
  *(bfrag8*)(x3b + base) = o;
}

// ------------- MFMA attention v3: 32x32x16, S^T route, no-max softmax,
// in-register P via cvt_pk + permlane32_swap; setprio around MFMA (T5) ------
__global__ __launch_bounds__(512, 4) void attn_kernel(
    const __bf16* __restrict__ Q, const __bf16* __restrict__ K,
    const __bf16* __restrict__ V, __bf16* __restrict__ av)
{
  __shared__ __bf16 Ks[196 * 64];
  __shared__ __bf16 Vt[64 * 208];

  int bid = blockIdx.x;
  int half = bid & 1;
  int h = (bid >> 1) & 7;
  int r0 = bid >> 4;               // 0..47
  int u = r0 % 12;
  int b = r0 / 12;

  const __bf16* Kp = K + ((size_t)(b * 12 + u) * 196) * 512 + h * 64;
  const __bf16* Vp = V + ((size_t)(b * 12 + u) * 196) * 512 + h * 64;

  for (int idx = threadIdx.x; idx < 196 * 8; idx += 512) {
    int r = idx >> 3, g = idx & 7;
    *(bfrag8*)&Ks[r * 64 + ((g ^ (r & 7)) * 8)] =
        *(const bfrag8*)&Kp[(size_t)r * 512 + g * 8];
  }
  for (int idx = threadIdx.x; idx < 64 * 6; idx += 512) {
    int r = idx / 6, c2 = 196 + (idx % 6) * 2;
    bf16p2 z; z.v[0] = (__bf16)0.f; z.v[1] = (__bf16)0.f;
    *(bf16p2*)&Vt[r * 208 + c2] = z;
  }
  for (int idx = threadIdx.x; idx < 98 * 8; idx += 512) {
    int r2 = (idx % 98) * 2, c8 = (idx / 98) * 8;
    bfrag8 va = *(const bfrag8*)&Vp[(size_t)r2 * 512 + c8];
    bfrag8 vb = *(const bfrag8*)&Vp[(size_t)(r2 + 1) * 512 + c8];
#pragma unroll
    for (int e = 0; e < 8; ++e) {
      bf16p2 pr; pr.v[0] = va[e]; pr.v[1] = vb[e];
      *(bf16p2*)&Vt[(c8 + e) * 208 + r2] = pr;
    }
  }
  __syncthreads();

  int w = threadIdx.x >> 6, l = threadIdx.x & 63;
  int l5 = l >> 5, c = l & 31;

  for (int unit = w; unit < 42; unit += 8) {
    int t = unit / 7, qt = unit - t * 7;
    int tq = half * 6 + t;
    const __bf16* Qp = Q + ((size_t)(b * 12 + tq) * 196) * 512 + h * 64;
    __bf16* avp = av + ((size_t)((b * 12 + tq) * 12 + u) * 196) * 512 + h * 64;
    int q0 = qt * 32;

    const __bf16* qp = Qp + (size_t)(q0 + c) * 512 + l5 * 8;
    bfrag8 qf[4];
    qf[0] = *(const bfrag8*)(qp);
    qf[1] = *(const bfrag8*)(qp + 16);
    qf[2] = *(const bfrag8*)(qp + 32);
    qf[3] = *(const bfrag8*)(qp + 48);

    ffrag16 O0, O1;
#pragma unroll
    for (int g = 0; g < 16; ++g) { O0[g] = 0.f; O1[g] = 0.f; }
    float sumacc = 0.f;

    // main loop: nt = 0..5, keys 0..191 (no boundary mask needed)
    for (int nt = 0; nt < 6; ++nt) {
      int key = nt * 32 + c;
      const __bf16* kbase = &Ks[key * 64];
      int kx = key & 7;

      ffrag16 s;
#pragma unroll
      for (int g = 0; g < 16; ++g) s[g] = 0.f;
      __builtin_amdgcn_s_setprio(1);
#pragma unroll
      for (int kc = 0; kc < 4; ++kc) {
        bfrag8 kf = *(const bfrag8*)&kbase[(((kc * 2 + l5) ^ kx) * 8)];
        s = __builtin_amdgcn_mfma_f32_32x32x16_bf16(kf, qf[kc], s, 0, 0, 0);
      }
      __builtin_amdgcn_s_setprio(0);

#pragma unroll
      for (int g = 0; g < 16; ++g) {
        float e = __expf(s[g] * 0.125f);
        s[g] = e;
        sumacc += e;
      }

#pragma unroll
      for (int sub = 0; sub < 2; ++sub) {
        int A0 = cvt_pk_bf16(s[sub * 8 + 0], s[sub * 8 + 1]);
        int A1 = cvt_pk_bf16(s[sub * 8 + 2], s[sub * 8 + 3]);
        int A2 = cvt_pk_bf16(s[sub * 8 + 4], s[sub * 8 + 5]);
        int A3 = cvt_pk_bf16(s[sub * 8 + 6], s[sub * 8 + 7]);
        perm_swap(A0, A2);   // A0 = word0 (k 0,1 | 8,9), A2 = word2 (k 4,5 | 12,13)
        perm_swap(A1, A3);   // A1 = word1, A3 = word3
        union { int i[4]; bfrag8 v; } pu;
        pu.i[0] = A0; pu.i[1] = A1; pu.i[2] = A2; pu.i[3] = A3;
        bfrag8 pa = pu.v;
        int ch = nt * 2 + sub;
        bfrag8 v0 = *(const bfrag8*)&Vt[(size_t)(c     ) * 208 + ch * 16 + l5 * 8];
        bfrag8 v1 = *(const bfrag8*)&Vt[(size_t)(c + 32) * 208 + ch * 16 + l5 * 8];
        __builtin_amdgcn_s_setprio(1);
        O0 = __builtin_amdgcn_mfma_f32_32x32x16_bf16(pa, v0, O0, 0, 0, 0);
        O1 = __builtin_amdgcn_mfma_f32_32x32x16_bf16(pa, v1, O1, 0, 0, 0);
        __builtin_amdgcn_s_setprio(0);
      }
    }

    // tail: nt = 6, keys 192..195 valid, one 16-key chunk
    {
      int key = 192 + c; if (key > 195) key = 195;
      const __bf16* kbase = &Ks[key * 64];
      int kx = key & 7;

      ffrag16 s;
#pragma unroll
      for (int g = 0; g < 16; ++g) s[g] = 0.f;
      __builtin_amdgcn_s_setprio(1);
#pragma unroll
      for (int kc = 0; kc < 4; ++kc) {
        bfrag8 kf = *(const bfrag8*)&kbase[(((kc * 2 + l5) ^ kx) * 8)];
        s = __builtin_amdgcn_mfma_f32_32x32x16_bf16(kf, qf[kc], s, 0, 0, 0);
      }
      __builtin_amdgcn_s_setprio(0);
#pragma unroll
      for (int g = 0; g < 16; ++g) {
        float e = __expf(s[g] * 0.125f);
        bool keep = (g < 4) && (l5 == 0);
        e = keep ? e : 0.f;
        s[g] = e;
        sumacc += e;
      }
      int A0 = cvt_pk_bf16(s[0], s[1]);
      int A1 = cvt_pk_bf16(s[2], s[3]);
      int A2 = cvt_pk_bf16(s[4], s[5]);
      int A3 = cvt_pk_bf16(s[6], s[7]);
      perm_swap(A0, A2);
      perm_swap(A1, A3);
      union { int i[4]; bfrag8 v; } pu;
      pu.i[0] = A0; pu.i[1] = A1; pu.i[2] = A2; pu.i[3] = A3;
      bfrag8 pa = pu.v;
      bfrag8 v0 = *(const bfrag8*)&Vt[(size_t)(c     ) * 208 + 12 * 16 + l5 * 8];
      bfrag8 v1 = *(const bfrag8*)&Vt[(size_t)(c + 32) * 208 + 12 * 16 + l5 * 8];
      __builtin_amdgcn_s_setprio(1);
      O0 = __builtin_amdgcn_mfma_f32_32x32x16_bf16(pa, v0, O0, 0, 0, 0);
      O1 = __builtin_amdgcn_mfma_f32_32x32x16_bf16(pa, v1, O1, 0, 0, 0);
      __builtin_amdgcn_s_setprio(0);
    }

    float stot = sumacc + __shfl_xor(sumacc, 32);

#pragma unroll
    for (int g = 0; g < 16; ++g) {
      int row = (g & 3) + 8 * (g >> 2) + 4 * l5;
      float sq = __shfl(stot, row);
      float iv = __builtin_amdgcn_rcpf(sq);
      int q = q0 + row;
      if (q < 196) {
        size_t base = (size_t)q * 512 + c;
        avp[base]      = (__bf16)(O0[g] * iv);
        avp[base + 32] = (__bf16)(O1[g] * iv);
      }
    }
  }
}

extern "C" void kernel_launch(void* const* d_in, const int* in_sizes, int n_in,
                              void* d_out, int out_size, void* d_ws, size_t ws_size,
                              hipStream_t stream)
{
  const float* x      = (const float*)d_in[0];
  const float* Wq     = (const float*)d_in[1];
  const float* bq     = (const float*)d_in[2];
  const float* Wk     = (const float*)d_in[3];
  const float* bk     = (const float*)d_in[4];
  const float* Wv     = (const float*)d_in[5];
  const float* bv     = (const float*)d_in[6];
  const float* in_a   = (const float*)d_in[7];
  const float* in_b   = (const float*)d_in[8];
  const float* attn_a = (const float*)d_in[9];
  const float* attn_b = (const float*)d_in[10];
  const float* out_a  = (const float*)d_in[11];
  const float* out_b  = (const float*)d_in[12];
  const float* Wt     = (const float*)d_in[13];
  const float* bt     = (const float*)d_in[14];
  const float* pos    = (const float*)d_in[15];
  const float* W1     = (const float*)d_in[16];
  const float* b1     = (const float*)d_in[17];
  const float* W2     = (const float*)d_in[18];
  const float* b2     = (const float*)d_in[19];

  char* ws = (char*)d_ws;
  const size_t bfb = (size_t)9408 * 512 * 2;       // 9,633,792 B (bf16 MxD)
  __bf16* x2b  = (__bf16*)(ws);
  __bf16* Qb   = (__bf16*)(ws + bfb);
  __bf16* Kb   = (__bf16*)(ws + 2 * bfb);
  __bf16* Vb   = (__bf16*)(ws + 3 * bfb);
  __bf16* av   = (__bf16*)(ws + 4 * bfb);          // 115,605,504 B
  char*   wreg = ws + 4 * bfb + (size_t)115605504; // weights bf16, 9,961,472 B
  __bf16* Wqb  = (__bf16*)(wreg);
  __bf16* Wkb  = (__bf16*)(wreg) + 262144;
  __bf16* Wvb  = (__bf16*)(wreg) + 524288;
  __bf16* W1b  = (__bf16*)(wreg) + 786432;
  __bf16* W2b  = (__bf16*)(wreg) + 1310720;
  __bf16* Wtb  = (__bf16*)(wreg) + 1835008;        // transposed [e][u*512+d]
  float*  sbt  = (float*)(wreg + 9961472);
  float*  acc0 = (float*)(wreg + 9963520);         // 19,267,584 B partial z=0
  // overlays (stream-ordered lifetimes):
  float*  acc1 = (float*)(ws + 2 * bfb);           // over Kb+Vb (dead after attn)
  float*  xmid = (float*)(ws);                     // over x2b+Qb
  __bf16* x3b  = (__bf16*)(ws + 4 * bfb + 33554432); // in av slab (dead after tc); hb uses first 19.3MB
  __bf16* hb   = (__bf16*)(ws + 4 * bfb);          // over av[0..19.3MB)
  float*  out  = (float*)d_out;

  conv_w_kernel<<<2432, 256, 0, stream>>>(Wq, Wk, Wv, W1, W2, Wt, (__bf16*)wreg);
  sum_bt_kernel<<<1, 512, 0, stream>>>(bt, sbt);
  norm_f32_to_bf16_kernel<<<9408, 64, 0, stream>>>(x, x2b, in_a, in_b);
  mfma_nt_kernel<<<dim3(12, 74), 512, 0, stream>>>(
      x2b, Wqb, Wkb, Wvb, bq, bk, bv, Qb, Kb, Vb, nullptr, nullptr, 512, 0);
  attn_kernel<<<768, 512, 0, stream>>>(Qb, Kb, Vb, av);
  norm_av_kernel<<<28224, 256, 0, stream>>>((bf16*)av, attn_a, attn_b, pos);
  mfma_tc_kernel<<<dim3(4, 74, 2), 512, 0, stream>>>(av, Wtb, acc0, acc1);
  tc_epi_norm_kernel<<<9408, 64, 0, stream>>>(acc0, acc1, x, sbt, out_a, out_b, xmid, x3b);
  mfma_nt_kernel<<<dim3(8, 74), 512, 0, stream>>>(
      x3b, W1b, nullptr, nullptr, b1, nullptr, nullptr, hb, nullptr, nullptr,
      nullptr, nullptr, 512, 1);
  mfma_nt_kernel<<<dim3(4, 74), 512, 0, stream>>>(
      hb, W2b, nullptr, nullptr, b2, nullptr, nullptr, nullptr, nullptr, nullptr,
      xmid, out, 1024, 2);
}

// Round 8
// 467.493 us; speedup vs baseline: 1.1214x; 1.0033x over previous
//
#include <hip/hip_runtime.h>
#include <hip/hip_bf16.h>

typedef __hip_bfloat16 bf16;

typedef __bf16 bfrag8 __attribute__((ext_vector_type(8)));
typedef __bf16 bfrag4 __attribute__((ext_vector_type(4)));
typedef float  ffrag4 __attribute__((ext_vector_type(4)));
typedef float  ffrag16 __attribute__((ext_vector_type(16)));

// B=4, T=12, P=196, D=512, H=8, DH=64 ; M = B*T*P = 9408 = 73.5*128
#define EPS 1e-6f

__device__ __forceinline__ float gelu_exact(float v) {
  return 0.5f * v * (1.0f + erff(v * 0.7071067811865475f));
}

__device__ __forceinline__ void async16(const void* g, void* s) {
  __builtin_amdgcn_global_load_lds(
      (const __attribute__((address_space(1))) unsigned int*)g,
      (__attribute__((address_space(3))) unsigned int*)s, 16, 0, 0);
}

// pack two f32 -> one dword of 2 bf16 (lo = a, hi = b)
__device__ __forceinline__ int cvt_pk_bf16(float a, float b) {
  int r;
  asm("v_cvt_pk_bf16_f32 %0, %1, %2" : "=v"(r) : "v"(a), "v"(b));
  return r;
}
// vdst.hi32lanes <-> vsrc.lo32lanes
__device__ __forceinline__ void perm_swap(int& a, int& b) {
  asm volatile("v_permlane32_swap_b32 %0, %1" : "+v"(a), "+v"(b));
}

struct alignas(16) bf16x8 { bf16 v[8]; };
struct alignas(4)  bf16p2 { __bf16 v[2]; };

// ---------------- weight convert f32 -> bf16, packed region ----------------
// Wt is transposed [u][e][d] -> [e][u][d] so tc's B-rows are contiguous (K=6144)
__global__ __launch_bounds__(256) void conv_w_kernel(
    const float* __restrict__ Wq, const float* __restrict__ Wk,
    const float* __restrict__ Wv, const float* __restrict__ W1,
    const float* __restrict__ W2, const float* __restrict__ Wt,
    __bf16* __restrict__ dst)
{
  size_t e = ((size_t)blockIdx.x * 256 + threadIdx.x) * 8;
  const float* src; size_t off, dsto;
  if      (e <  262144) { src = Wq; off = e;           dsto = e; }
  else if (e <  524288) { src = Wk; off = e -  262144; dsto = e; }
  else if (e <  786432) { src = Wv; off = e -  524288; dsto = e; }
  else if (e < 1310720) { src = W1; off = e -  786432; dsto = e; }
  else if (e < 1835008) { src = W2; off = e - 1310720; dsto = e; }
  else if (e < 4980736) {
    src = Wt; off = e - 1835008;
    size_t u = off >> 18;            // / (512*512)
    size_t rem = off & 262143;
    size_t eo = rem >> 9, d = rem & 511;
    dsto = 1835008 + eo * 6144 + u * 512 + d;   // [e][u*512+d]
  }
  else return;
  float4 f0 = *(const float4*)(src + off);
  float4 f1 = *(const float4*)(src + off + 4);
  bfrag8 o;
  o[0] = (__bf16)f0.x; o[1] = (__bf16)f0.y; o[2] = (__bf16)f0.z; o[3] = (__bf16)f0.w;
  o[4] = (__bf16)f1.x; o[5] = (__bf16)f1.y; o[6] = (__bf16)f1.z; o[7] = (__bf16)f1.w;
  *(bfrag8*)(dst + dsto) = o;
}

__global__ __launch_bounds__(512) void sum_bt_kernel(
    const float* __restrict__ bt, float* __restrict__ sbt)
{
  int n = threadIdx.x;
  float s = 0.f;
#pragma unroll
  for (int u = 0; u < 12; ++u) s += bt[u * 512 + n];
  sbt[n] = s;
}

// ------------- LayerNorm f32 -> bf16, one 64-thread block per row of 512 ----
__global__ __launch_bounds__(64) void norm_f32_to_bf16_kernel(
    const float* __restrict__ in, __bf16* __restrict__ out,
    const float* __restrict__ alpha, const float* __restrict__ beta)
{
  size_t row = blockIdx.x;
  int l = threadIdx.x;
  const float* r = in + row * 512 + l * 8;
  float4 v0 = *(const float4*)(r);
  float4 v1 = *(const float4*)(r + 4);
  float f[8] = {v0.x, v0.y, v0.z, v0.w, v1.x, v1.y, v1.z, v1.w};
  float s = 0.f, ss = 0.f;
#pragma unroll
  for (int q = 0; q < 8; ++q) { s += f[q]; ss += f[q] * f[q]; }
#pragma unroll
  for (int off = 32; off; off >>= 1) { s += __shfl_xor(s, off); ss += __shfl_xor(ss, off); }
  float mu = s * (1.f / 512.f);
  float var = fmaxf((ss - 512.f * mu * mu) * (1.f / 511.f), 0.f);
  float inv = 1.f / (sqrtf(var) + EPS);
  const float* al = alpha + l * 8;
  const float* be = beta + l * 8;
  float4 a0 = *(const float4*)al, a1 = *(const float4*)(al + 4);
  float4 b0 = *(const float4*)be, b1 = *(const float4*)(be + 4);
  float aa[8] = {a0.x, a0.y, a0.z, a0.w, a1.x, a1.y, a1.z, a1.w};
  float bb[8] = {b0.x, b0.y, b0.z, b0.w, b1.x, b1.y, b1.z, b1.w};
  bfrag8 o;
#pragma unroll
  for (int q = 0; q < 8; ++q) o[q] = (__bf16)(aa[q] * (f[q] - mu) * inv + bb[q]);
  *(bfrag8*)(out + row * 512 + l * 8) = o;
}

// ------------- LayerNorm bf16 in-place + pos add; 4 rows per 256-thr block --
__global__ __launch_bounds__(256) void norm_av_kernel(
    bf16* __restrict__ av, const float* __restrict__ alpha,
    const float* __restrict__ beta, const float* __restrict__ pos)
{
  size_t row = (size_t)blockIdx.x * 4 + (threadIdx.x >> 6);  // [0, B*T*T*P)
  int l = threadIdx.x & 63;
  bf16* r = av + row * 512 + (size_t)l * 8;
  bf16x8 ib = *(const bf16x8*)r;
  float f[8];
#pragma unroll
  for (int q = 0; q < 8; ++q) f[q] = __bfloat162float(ib.v[q]);
  float s = 0.f, ss = 0.f;
#pragma unroll
  for (int q = 0; q < 8; ++q) { s += f[q]; ss += f[q] * f[q]; }
#pragma unroll
  for (int off = 32; off; off >>= 1) { s += __shfl_xor(s, off); ss += __shfl_xor(ss, off); }
  float mu = s * (1.f / 512.f);
  float var = fmaxf((ss - 512.f * mu * mu) * (1.f / 511.f), 0.f);
  float inv = 1.f / (sqrtf(var) + EPS);
  size_t prow = row % 28224;        // T*T*P  (pos broadcasts over batch)
  const float* pr = pos + prow * 512 + l * 8;
  float4 p0 = *(const float4*)pr, p1 = *(const float4*)(pr + 4);
  const float* al = alpha + l * 8;
  const float* be = beta + l * 8;
  float4 a0 = *(const float4*)al, a1 = *(const float4*)(al + 4);
  float4 b0 = *(const float4*)be, b1 = *(const float4*)(be + 4);
  float pa[8] = {p0.x, p0.y, p0.z, p0.w, p1.x, p1.y, p1.z, p1.w};
  float aa[8] = {a0.x, a0.y, a0.z, a0.w, a1.x, a1.y, a1.z, a1.w};
  float bb[8] = {b0.x, b0.y, b0.z, b0.w, b1.x, b1.y, b1.z, b1.w};
  bf16x8 ob;
#pragma unroll
  for (int q = 0; q < 8; ++q)
    ob.v[q] = __float2bfloat16(aa[q] * (f[q] - mu) * inv + bb[q] + pa[q]);
  *(bf16x8*)r = ob;
}

// ------------- MFMA NT GEMM, 128x128 tile, BK=32, 3-buffer pipeline ---------
// 512 threads / 8 waves, each wave a 32x64 sub-tile (2x4 frags, 8 MFMA/step)
// -> 6 waves/SIMD resident (3 blocks/CU) to hide ds_read + barrier stalls.
// Depth-2 prefetch, ONE raw barrier per K-step, counted vmcnt(2).
// LDS slot swizzle on both sides. Chunked XCD swizzle.
// mode 0: fused QKV (N=1536), out bf16 +bias; mode 1: MLP1, out bf16 gelu;
// mode 2: MLP2, out f32 = res + gelu(acc+bias)
__global__ __launch_bounds__(512) void mfma_nt_kernel(
    const __bf16* __restrict__ A,
    const __bf16* __restrict__ Bq, const __bf16* __restrict__ Bk,
    const __bf16* __restrict__ Bv,
    const float* __restrict__ bq, const float* __restrict__ bk,
    const float* __restrict__ bv,
    __bf16* __restrict__ oq, __bf16* __restrict__ ok, __bf16* __restrict__ ov,
    const float* __restrict__ res, float* __restrict__ fout,
    int K, int mode)
{
  __shared__ __bf16 As[3 * 128 * 32];
  __shared__ __bf16 Bs[3 * 128 * 32];
  int tid = threadIdx.x;

  // chunked XCD swizzle (bijective; nwg % 8 == 0 for all our grids)
  int nwg = gridDim.x * gridDim.y;
  int cpx = nwg >> 3;
  int lid = blockIdx.x + gridDim.x * blockIdx.y;
  int logical = (lid & 7) * cpx + (lid >> 3);
  int bx = logical % gridDim.x;
  int by = logical / gridDim.x;
  int m0 = by * 128;
  int n0g = bx * 128;

  const __bf16* Bsel; const float* biassel; __bf16* osel; int ncol0;
  if (mode == 0) {
    int sel = n0g >> 9;
    Bsel = sel == 0 ? Bq : (sel == 1 ? Bk : Bv);
    biassel = sel == 0 ? bq : (sel == 1 ? bk : bv);
    osel = sel == 0 ? oq : (sel == 1 ? ok : ov);
    ncol0 = n0g & 511;
  } else {
    Bsel = Bq; biassel = bq; osel = oq; ncol0 = n0g;
  }

  int srow = tid >> 2;                              // 0..127
  int scol = ((tid & 3) ^ ((srow >> 1) & 3)) * 8;   // pre-swizzled source slot
  int rg0 = m0 + srow;       if (rg0 > 9407) rg0 = 9407;
  const __bf16* a0 = A + (size_t)rg0 * K + scol;
  const __bf16* b0 = Bsel + (size_t)(ncol0 + srow) * K + scol;
  char* sa0 = (char*)As + tid * 16;
  char* sb0 = (char*)Bs + tid * 16;

  int l = tid & 63, w = tid >> 6;                   // 8 waves
  int lm = l & 15, lq = l >> 4;
  int wm = w >> 1, wn = w & 1;                      // 4x2 wave grid, 32x64 each
  int rsw = ((((lm >> 1) & 3) ^ lq)) * 8;           // swizzled read slot

  const int nsteps = K >> 5;
  // prologue: stage steps 0 and 1 into bufs 0 and 1 (one async16 per panel)
  async16(a0, sa0); async16(b0, sb0);
  async16(a0 + 32, sa0 + 8192); async16(b0 + 32, sb0 + 8192);
  __builtin_amdgcn_sched_barrier(0);
  asm volatile("s_waitcnt vmcnt(2)" ::: "memory");   // step-0 loads landed
  __builtin_amdgcn_s_barrier();
  __builtin_amdgcn_sched_barrier(0);

  ffrag4 acc[2][4] = {};
  int cur = 0;
  for (int t = 0; t < nsteps; ++t) {
    if (t + 2 < nsteps) {                 // issue depth-2 prefetch
      int k2 = (t + 2) << 5;
      int nb = cur + 2; if (nb >= 3) nb -= 3;
      int bo = nb * 8192;
      async16(a0 + k2, sa0 + bo); async16(b0 + k2, sb0 + bo);
    }
    int co = cur * 4096;
    bfrag8 af[2], bfr[4];
#pragma unroll
    for (int i = 0; i < 2; ++i)
      af[i] = *(const bfrag8*)&As[co + (wm * 32 + i * 16 + lm) * 32 + rsw];
#pragma unroll
    for (int j = 0; j < 4; ++j)
      bfr[j] = *(const bfrag8*)&Bs[co + (wn * 64 + j * 16 + lm) * 32 + rsw];
#pragma unroll
    for (int i = 0; i < 2; ++i)
#pragma unroll
      for (int j = 0; j < 4; ++j)
        acc[i][j] = __builtin_amdgcn_mfma_f32_16x16x32_bf16(af[i], bfr[j], acc[i][j], 0, 0, 0);
    __builtin_amdgcn_sched_barrier(0);
    if (t + 2 < nsteps) asm volatile("s_waitcnt vmcnt(2)" ::: "memory");
    else                asm volatile("s_waitcnt vmcnt(0)" ::: "memory");
    __builtin_amdgcn_s_barrier();
    __builtin_amdgcn_sched_barrier(0);
    cur += 1; if (cur == 3) cur = 0;
  }

#pragma unroll
  for (int i = 0; i < 2; ++i) {
    int mbase = m0 + wm * 32 + i * 16 + lq * 4;
#pragma unroll
    for (int j = 0; j < 4; ++j) {
      int n = ncol0 + wn * 64 + j * 16 + lm;
      float bj = biassel[n];
#pragma unroll
      for (int r = 0; r < 4; ++r) {
        int mr = mbase + r;
        if (mr < 9408) {
          float v = acc[i][j][r] + bj;
          if (mode == 0)      osel[(size_t)mr * 512 + n] = (__bf16)v;
          else if (mode == 1) osel[(size_t)mr * 1024 + n] = (__bf16)gelu_exact(v);
          else                fout[(size_t)mr * 512 + n] =
                                res[(size_t)mr * 512 + n] + gelu_exact(v);
        }
      }
    }
  }
}

// ------- temporal mixing as one flat NT GEMM: M=9408, N=512, K=6144 (u,d) ---
// z splits K 2-way; each z writes its OWN partial buffer with plain stores
// (NO atomics, no pre-zero). tc_epi sums the two partials.
// 512 threads / 8 waves / 32x64 sub-tiles; 3-buffer depth-2 counted-vmcnt
// pipeline; chunked XCD swizzle.
__global__ __launch_bounds__(512) void mfma_tc_kernel(
    const __bf16* __restrict__ X2p, const __bf16* __restrict__ Wte,
    float* __restrict__ acc0, float* __restrict__ acc1)
{
  __shared__ __bf16 As[3 * 128 * 32];
  __shared__ __bf16 Bs[3 * 128 * 32];
  int tid = threadIdx.x;

  // grid (4,74,2) -> nwg=592=8*74, chunked XCD swizzle
  int lid = blockIdx.x + 4 * (blockIdx.y + 74 * blockIdx.z);
  int logical = (lid & 7) * 74 + (lid >> 3);
  int lx = logical & 3;
  int rest = logical >> 2;         // ly + 74*lz
  int ly = rest % 74;
  int lz = rest / 74;

  int m0 = ly * 128;
  int n0 = lx * 128;
  int kbeg = lz * 3072;            // 96 K-steps per block
  float* accp = lz == 0 ? acc0 : acc1;

  int srow = tid >> 2;             // 0..127
  int scol = ((tid & 3) ^ ((srow >> 1) & 3)) * 8;
  int rg0 = m0 + srow;       if (rg0 > 9407) rg0 = 9407;
  int btq0 = rg0 / 196, p0_ = rg0 - btq0 * 196;
  const __bf16* a0 = X2p + (size_t)btq0 * 1204224 + (size_t)p0_ * 512 + scol;
  const __bf16* b0 = Wte + (size_t)(n0 + srow) * 6144 + scol;
  char* sa0 = (char*)As + tid * 16;
  char* sb0 = (char*)Bs + tid * 16;

  int l = tid & 63, w = tid >> 6;
  int lm = l & 15, lq = l >> 4;
  int wm = w >> 1, wn = w & 1;
  int rsw = ((((lm >> 1) & 3) ^ lq)) * 8;

  // prologue: stage steps 0 and 1 into bufs 0 and 1
  {
    size_t ao0 = (size_t)(kbeg >> 9) * 100352 + (size_t)(kbeg & 511);
    int k1 = kbeg + 32;
    size_t ao1 = (size_t)(k1 >> 9) * 100352 + (size_t)(k1 & 511);
    async16(a0 + ao0, sa0); async16(b0 + kbeg, sb0);
    async16(a0 + ao1, sa0 + 8192); async16(b0 + k1, sb0 + 8192);
  }
  __builtin_amdgcn_sched_barrier(0);
  asm volatile("s_waitcnt vmcnt(2)" ::: "memory");
  __builtin_amdgcn_s_barrier();
  __builtin_amdgcn_sched_barrier(0);

  ffrag4 acc[2][4] = {};
  int cur = 0;
  for (int t = 0; t < 96; ++t) {
    if (t + 2 < 96) {
      int k2 = kbeg + (t + 2) * 32;
      size_t aoff = (size_t)(k2 >> 9) * 100352 + (size_t)(k2 & 511);
      int nb = cur + 2; if (nb >= 3) nb -= 3;
      int bo = nb * 8192;
      async16(a0 + aoff, sa0 + bo); async16(b0 + k2, sb0 + bo);
    }
    int co = cur * 4096;
    bfrag8 af[2], bfr[4];
#pragma unroll
    for (int i = 0; i < 2; ++i)
      af[i] = *(const bfrag8*)&As[co + (wm * 32 + i * 16 + lm) * 32 + rsw];
#pragma unroll
    for (int j = 0; j < 4; ++j)
      bfr[j] = *(const bfrag8*)&Bs[co + (wn * 64 + j * 16 + lm) * 32 + rsw];
#pragma unroll
    for (int i = 0; i < 2; ++i)
#pragma unroll
      for (int j = 0; j < 4; ++j)
        acc[i][j] = __builtin_amdgcn_mfma_f32_16x16x32_bf16(af[i], bfr[j], acc[i][j], 0, 0, 0);
    __builtin_amdgcn_sched_barrier(0);
    if (t + 2 < 96) asm volatile("s_waitcnt vmcnt(2)" ::: "memory");
    else            asm volatile("s_waitcnt vmcnt(0)" ::: "memory");
    __builtin_amdgcn_s_barrier();
    __builtin_amdgcn_sched_barrier(0);
    cur += 1; if (cur == 3) cur = 0;
  }

#pragma unroll
  for (int i = 0; i < 2; ++i) {
    int mbase = m0 + wm * 32 + i * 16 + lq * 4;
#pragma unroll
    for (int j = 0; j < 4; ++j) {
      int n = n0 + wn * 64 + j * 16 + lm;
#pragma unroll
      for (int r = 0; r < 4; ++r) {
        int mr = mbase + r;
        if (mr < 9408)
          accp[(size_t)mr * 512 + n] = acc[i][j][r];
      }
    }
  }
}

// ------- tc epilogue + out-LN fused: xmid = x + gelu((p0+p1)/12 + sbt); x3b = LN(xmid)
__global__ __launch_bounds__(64) void tc_epi_norm_kernel(
    const float* __restrict__ acc0, const float* __restrict__ acc1,
    const float* __restrict__ x, const float* __restrict__ sbt,
    const float* __restrict__ alpha, const float* __restrict__ beta,
    float* __restrict__ xmid, __bf16* __restrict__ x3b)
{
  size_t row = blockIdx.x;
  int l = threadIdx.x;
  size_t base = row * 512 + l * 8;
  float4 c0 = *(const float4*)(acc0 + base);
  float4 c1 = *(const float4*)(acc0 + base + 4);
  float4 d0 = *(const float4*)(acc1 + base);
  float4 d1 = *(const float4*)(acc1 + base + 4);
  float4 x0 = *(const float4*)(x + base);
  float4 x1 = *(const float4*)(x + base + 4);
  float4 s0 = *(const float4*)(sbt + l * 8);
  float4 s1 = *(const float4*)(sbt + l * 8 + 4);
  float cc[8] = {c0.x + d0.x, c0.y + d0.y, c0.z + d0.z, c0.w + d0.w,
                 c1.x + d1.x, c1.y + d1.y, c1.z + d1.z, c1.w + d1.w};
  float xx[8] = {x0.x, x0.y, x0.z, x0.w, x1.x, x1.y, x1.z, x1.w};
  float sv[8] = {s0.x, s0.y, s0.z, s0.w, s1.x, s1.y, s1.z, s1.w};
  float f[8];
#pragma unroll
  for (int q = 0; q < 8; ++q)
    f[q] = xx[q] + gelu_exact(cc[q] * (1.f / 12.f) + sv[q]);
  *(float4*)(xmid + base)     = make_float4(f[0], f[1], f[2], f[3]);
  *(float4*)(xmid + base + 4) = make_float4(f[4], f[5], f[6], f[7]);
  float s = 0.f, ss = 0.f;
#pragma unroll
  for (int q = 0; q < 8; ++q) { s += f[q]; ss += f[q] * f[q]; }
#pragma unroll
  for (int off = 32; off; off >>= 1) { s += __shfl_xor(s, off); ss += __shfl_xor(ss, off); }
  float mu = s * (1.f / 512.f);
  float var = fmaxf((ss - 512.f * mu * mu) * (1.f / 511.f), 0.f);
  float inv = 1.f / (sqrtf(var) + EPS);
  const float* al = alpha + l * 8;
  const float* be = beta + l * 8;
  float4 a0 = *(const float4*)al, a1 = *(const float4*)(al + 4);
  float4 b0 = *(const float4*)be, b1 = *(const float4*)(be + 4);
  float aa[8] = {a0.x, a0.y, a0.z, a0.w, a1.x, a1.y, a1.z, a1.w};
  float bb[8] = {b0.x, b0.y, b0.z, b0.w, b1.x, b1.y, b1.z, b1.w};
  bfrag8 o;
#pragma unroll
  for (int q = 0; q < 8; ++q) o[q] = (__bf16)(aa[q] * (f[q] - mu) * inv + bb[q]);
  *(bfrag8*)(x3b + base) = o;
}

// ------------- MFMA attention v4: 32x32x16, S^T route, no-max softmax,
// in-register P (cvt_pk + permlane32_swap), Vt slot-XOR swizzle (row&3) to
// kill the 8-way PV bank conflict; setprio around MFMA (T5) -----------------
__global__ __launch_bounds__(512, 4) void attn_kernel(
    const __bf16* __restrict__ Q, const __bf16* __restrict__ K,
    const __bf16* __restrict__ V, __bf16* __restrict__ av)
{
  __shared__ __bf16 Ks[196 * 64];
  __shared__ __bf16 Vt[64 * 224];   // rows padded 208->224; 16B-slot XOR (row&3)

  int bid = blockIdx.x;
  int half = bid & 1;
  int h = (bid >> 1) & 7;
  int r0 = bid >> 4;               // 0..47
  int u = r0 % 12;
  int b = r0 / 12;

  const __bf16* Kp = K + ((size_t)(b * 12 + u) * 196) * 512 + h * 64;
  const __bf16* Vp = V + ((size_t)(b * 12 + u) * 196) * 512 + h * 64;

  for (int idx = threadIdx.x; idx < 196 * 8; idx += 512) {
    int r = idx >> 3, g = idx & 7;
    *(bfrag8*)&Ks[r * 64 + ((g ^ (r & 7)) * 8)] =
        *(const bfrag8*)&Kp[(size_t)r * 512 + g * 8];
  }
  // zero-fill pad keys 196..207 (swizzled addresses)
  for (int idx = threadIdx.x; idx < 64 * 6; idx += 512) {
    int r = idx / 6, c2 = 196 + (idx % 6) * 2;
    int sl = (c2 >> 3) ^ (r & 3);
    bf16p2 z; z.v[0] = (__bf16)0.f; z.v[1] = (__bf16)0.f;
    *(bf16p2*)&Vt[r * 224 + sl * 8 + (c2 & 7)] = z;
  }
  // V transpose staging (swizzled: slot' = slot ^ (row&3))
  for (int idx = threadIdx.x; idx < 98 * 8; idx += 512) {
    int r2 = (idx % 98) * 2, c8 = (idx / 98) * 8;
    bfrag8 va = *(const bfrag8*)&Vp[(size_t)r2 * 512 + c8];
    bfrag8 vb = *(const bfrag8*)&Vp[(size_t)(r2 + 1) * 512 + c8];
#pragma unroll
    for (int e = 0; e < 8; ++e) {
      int d = c8 + e;
      int sl = (r2 >> 3) ^ (d & 3);
      bf16p2 pr; pr.v[0] = va[e]; pr.v[1] = vb[e];
      *(bf16p2*)&Vt[d * 224 + sl * 8 + (r2 & 7)] = pr;
    }
  }
  __syncthreads();

  int w = threadIdx.x >> 6, l = threadIdx.x & 63;
  int l5 = l >> 5, c = l & 31;
  int vsw = c & 3;                  // row-XOR for Vt reads ((c+32)&3 == c&3)

  for (int unit = w; unit < 42; unit += 8) {
    int t = unit / 7, qt = unit - t * 7;
    int tq = half * 6 + t;
    const __bf16* Qp = Q + ((size_t)(b * 12 + tq) * 196) * 512 + h * 64;
    __bf16* avp = av + ((size_t)((b * 12 + tq) * 12 + u) * 196) * 512 + h * 64;
    int q0 = qt * 32;

    const __bf16* qp = Qp + (size_t)(q0 + c) * 512 + l5 * 8;
    bfrag8 qf[4];
    qf[0] = *(const bfrag8*)(qp);
    qf[1] = *(const bfrag8*)(qp + 16);
    qf[2] = *(const bfrag8*)(qp + 32);
    qf[3] = *(const bfrag8*)(qp + 48);

    ffrag16 O0, O1;
#pragma unroll
    for (int g = 0; g < 16; ++g) { O0[g] = 0.f; O1[g] = 0.f; }
    float sumacc = 0.f;

    // main loop: nt = 0..5, keys 0..191 (no boundary mask needed)
    for (int nt = 0; nt < 6; ++nt) {
      int key = nt * 32 + c;
      const __bf16* kbase = &Ks[key * 64];
      int kx = key & 7;

      ffrag16 s;
#pragma unroll
      for (int g = 0; g < 16; ++g) s[g] = 0.f;
      __builtin_amdgcn_s_setprio(1);
#pragma unroll
      for (int kc = 0; kc < 4; ++kc) {
        bfrag8 kf = *(const bfrag8*)&kbase[(((kc * 2 + l5) ^ kx) * 8)];
        s = __builtin_amdgcn_mfma_f32_32x32x16_bf16(kf, qf[kc], s, 0, 0, 0);
      }
      __builtin_amdgcn_s_setprio(0);

#pragma unroll
      for (int g = 0; g < 16; ++g) {
        float e = __expf(s[g] * 0.125f);
        s[g] = e;
        sumacc += e;
      }

#pragma unroll
      for (int sub = 0; sub < 2; ++sub) {
        int A0 = cvt_pk_bf16(s[sub * 8 + 0], s[sub * 8 + 1]);
        int A1 = cvt_pk_bf16(s[sub * 8 + 2], s[sub * 8 + 3]);
        int A2 = cvt_pk_bf16(s[sub * 8 + 4], s[sub * 8 + 5]);
        int A3 = cvt_pk_bf16(s[sub * 8 + 6], s[sub * 8 + 7]);
        perm_swap(A0, A2);   // A0 = word0 (k 0,1 | 8,9), A2 = word2 (k 4,5 | 12,13)
        perm_swap(A1, A3);   // A1 = word1, A3 = word3
        union { int i[4]; bfrag8 v; } pu;
        pu.i[0] = A0; pu.i[1] = A1; pu.i[2] = A2; pu.i[3] = A3;
        bfrag8 pa = pu.v;
        int ch = nt * 2 + sub;
        int sl = ((ch * 2 + l5) ^ vsw) * 8;
        bfrag8 v0 = *(const bfrag8*)&Vt[(size_t)(c     ) * 224 + sl];
        bfrag8 v1 = *(const bfrag8*)&Vt[(size_t)(c + 32) * 224 + sl];
        __builtin_amdgcn_s_setprio(1);
        O0 = __builtin_amdgcn_mfma_f32_32x32x16_bf16(pa, v0, O0, 0, 0, 0);
        O1 = __builtin_amdgcn_mfma_f32_32x32x16_bf16(pa, v1, O1, 0, 0, 0);
        __builtin_amdgcn_s_setprio(0);
      }
    }

    // tail: nt = 6, keys 192..195 valid, one 16-key chunk (ch = 12)
    {
      int key = 192 + c; if (key > 195) key = 195;
      const __bf16* kbase = &Ks[key * 64];
      int kx = key & 7;

      ffrag16 s;
#pragma unroll
      for (int g = 0; g < 16; ++g) s[g] = 0.f;
      __builtin_amdgcn_s_setprio(1);
#pragma unroll
      for (int kc = 0; kc < 4; ++kc) {
        bfrag8 kf = *(const bfrag8*)&kbase[(((kc * 2 + l5) ^ kx) * 8)];
        s = __builtin_amdgcn_mfma_f32_32x32x16_bf16(kf, qf[kc], s, 0, 0, 0);
      }
      __builtin_amdgcn_s_setprio(0);
#pragma unroll
      for (int g = 0; g < 16; ++g) {
        float e = __expf(s[g] * 0.125f);
        bool keep = (g < 4) && (l5 == 0);
        e = keep ? e : 0.f;
        s[g] = e;
        sumacc += e;
      }
      int A0 = cvt_pk_bf16(s[0], s[1]);
      int A1 = cvt_pk_bf16(s[2], s[3]);
      int A2 = cvt_pk_bf16(s[4], s[5]);
      int A3 = cvt_pk_bf16(s[6], s[7]);
      perm_swap(A0, A2);
      perm_swap(A1, A3);
      union { int i[4]; bfrag8 v; } pu;
      pu.i[0] = A0; pu.i[1] = A1; pu.i[2] = A2; pu.i[3] = A3;
      bfrag8 pa = pu.v;
      int sl = ((24 + l5) ^ vsw) * 8;
      bfrag8 v0 = *(const bfrag8*)&Vt[(size_t)(c     ) * 224 + sl];
      bfrag8 v1 = *(const bfrag8*)&Vt[(size_t)(c + 32) * 224 + sl];
      __builtin_amdgcn_s_setprio(1);
      O0 = __builtin_amdgcn_mfma_f32_32x32x16_bf16(pa, v0, O0, 0, 0, 0);
      O1 = __builtin_amdgcn_mfma_f32_32x32x16_bf16(pa, v1, O1, 0, 0, 0);
      __builtin_amdgcn_s_setprio(0);
    }

    float stot = sumacc + __shfl_xor(sumacc, 32);

#pragma unroll
    for (int g = 0; g < 16; ++g) {
      int row = (g & 3) + 8 * (g >> 2) + 4 * l5;
      float sq = __shfl(stot, row);
      float iv = __builtin_amdgcn_rcpf(sq);
      int q = q0 + row;
      if (q < 196) {
        size_t base = (size_t)q * 512 + c;
        avp[base]      = (__bf16)(O0[g] * iv);
        avp[base + 32] = (__bf16)(O1[g] * iv);
      }
    }
  }
}

extern "C" void kernel_launch(void* const* d_in, const int* in_sizes, int n_in,
                              void* d_out, int out_size, void* d_ws, size_t ws_size,
                              hipStream_t stream)
{
  const float* x      = (const float*)d_in[0];
  const float* Wq     = (const float*)d_in[1];
  const float* bq     = (const float*)d_in[2];
  const float* Wk     = (const float*)d_in[3];
  const float* bk     = (const float*)d_in[4];
  const float* Wv     = (const float*)d_in[5];
  const float* bv     = (const float*)d_in[6];
  const float* in_a   = (const float*)d_in[7];
  const float* in_b   = (const float*)d_in[8];
  const float* attn_a = (const float*)d_in[9];
  const float* attn_b = (const float*)d_in[10];
  const float* out_a  = (const float*)d_in[11];
  const float* out_b  = (const float*)d_in[12];
  const float* Wt     = (const float*)d_in[13];
  const float* bt     = (const float*)d_in[14];
  const float* pos    = (const float*)d_in[15];
  const float* W1     = (const float*)d_in[16];
  const float* b1     = (const float*)d_in[17];
  const float* W2     = (const float*)d_in[18];
  const float* b2     = (const float*)d_in[19];

  char* ws = (char*)d_ws;
  const size_t bfb = (size_t)9408 * 512 * 2;       // 9,633,792 B (bf16 MxD)
  __bf16* x2b  = (__bf16*)(ws);
  __bf16* Qb   = (__bf16*)(ws + bfb);
  __bf16* Kb   = (__bf16*)(ws + 2 * bfb);
  __bf16* Vb   = (__bf16*)(ws + 3 * bfb);
  __bf16* av   = (__bf16*)(ws + 4 * bfb);          // 115,605,504 B
  char*   wreg = ws + 4 * bfb + (size_t)115605504; // weights bf16, 9,961,472 B
  __bf16* Wqb  = (__bf16*)(wreg);
  __bf16* Wkb  = (__bf16*)(wreg) + 262144;
  __bf16* Wvb  = (__bf16*)(wreg) + 524288;
  __bf16* W1b  = (__bf16*)(wreg) + 786432;
  __bf16* W2b  = (__bf16*)(wreg) + 1310720;
  __bf16* Wtb  = (__bf16*)(wreg) + 1835008;        // transposed [e][u*512+d]
  float*  sbt  = (float*)(wreg + 9961472);
  float*  acc0 = (float*)(wreg + 9963520);         // 19,267,584 B partial z=0
  // overlays (stream-ordered lifetimes):
  float*  acc1 = (float*)(ws + 2 * bfb);           // over Kb+Vb (dead after attn)
  float*  xmid = (float*)(ws);                     // over x2b+Qb
  __bf16* x3b  = (__bf16*)(ws + 4 * bfb + 33554432); // in av slab (dead after tc); hb uses first 19.3MB
  __bf16* hb   = (__bf16*)(ws + 4 * bfb);          // over av[0..19.3MB)
  float*  out  = (float*)d_out;

  conv_w_kernel<<<2432, 256, 0, stream>>>(Wq, Wk, Wv, W1, W2, Wt, (__bf16*)wreg);
  sum_bt_kernel<<<1, 512, 0, stream>>>(bt, sbt);
  norm_f32_to_bf16_kernel<<<9408, 64, 0, stream>>>(x, x2b, in_a, in_b);
  mfma_nt_kernel<<<dim3(12, 74), 512, 0, stream>>>(
      x2b, Wqb, Wkb, Wvb, bq, bk, bv, Qb, Kb, Vb, nullptr, nullptr, 512, 0);
  attn_kernel<<<768, 512, 0, stream>>>(Qb, Kb, Vb, av);
  norm_av_kernel<<<28224, 256, 0, stream>>>((bf16*)av, attn_a, attn_b, pos);
  mfma_tc_kernel<<<dim3(4, 74, 2), 512, 0, stream>>>(av, Wtb, acc0, acc1);
  tc_epi_norm_kernel<<<9408, 64, 0, stream>>>(acc0, acc1, x, sbt, out_a, out_b, xmid, x3b);
  mfma_nt_kernel<<<dim3(8, 74), 512, 0, stream>>>(
      x3b, W1b, nullptr, nullptr, b1, nullptr, nullptr, hb, nullptr, nullptr,
      nullptr, nullptr, 512, 1);
  mfma_nt_kernel<<<dim3(4, 74), 512, 0, stream>>>(
      hb, W2b, nullptr, nullptr, b2, nullptr, nullptr, nullptr, nullptr, nullptr,
      xmid, out, 1024, 2);
}